// Round 2
// baseline (3124.396 us; speedup 1.0000x reference)
//
#include <hip/hip_runtime.h>

typedef unsigned short ushortT;
typedef short bf16x8 __attribute__((ext_vector_type(8)));
typedef float f32x4 __attribute__((ext_vector_type(4)));
typedef unsigned int u32x4 __attribute__((ext_vector_type(4)));

// EqProp free phase, B=4096, layers [10,512,512 | x=784 clamped], T=30, DT=0.5.
// States in [0,1] always => rho(s)=s, rhop(s)=1.
// Internal state: bf16, padded row stride 1040: [0,10)=s0, [16,528)=s1, [528,1040)=s2.
// Output (t=29): fp32 packed stride 1034: [0,10)|[10,522)|[522,1034).
#define BATCH 4096
#define SPAD 1040
#define OFF1B 16
#define OFF2B 528
#define CSTR 1034
#define OFF1P 10
#define OFF2P 522

__device__ __forceinline__ ushortT f2b(float f) {
    union { float f; unsigned u; } v; v.f = f;
    unsigned r = (v.u + 0x7FFFu + ((v.u >> 16) & 1u)) >> 16;  // RNE
    return (ushortT)r;
}
__device__ __forceinline__ float b2f(ushortT b) {
    union { unsigned u; float f; } v; v.u = ((unsigned)b) << 16;
    return v.f;
}

// ---------------- zero bf16 state buffer ----------------
__global__ void k_zero(u32x4* __restrict__ p, int n) {
    u32x4 z = {0u, 0u, 0u, 0u};
    for (int i = blockIdx.x * blockDim.x + threadIdx.x; i < n; i += gridDim.x * blockDim.x)
        p[i] = z;
}

// ---------------- weight prep: W1 -> bf16 row-major + bf16 transpose ----------------
__global__ __launch_bounds__(256) void k_prep(const float* __restrict__ W1,
                                              ushortT* __restrict__ W1bf,
                                              ushortT* __restrict__ W1T) {
    __shared__ float tile[64][65];
    const int ti = blockIdx.x >> 3, tj = blockIdx.x & 7;
    const int t = threadIdx.x;
#pragma unroll
    for (int q = 0; q < 16; ++q) {
        int rr = q * 4 + (t >> 6), cc = t & 63;
        float v = W1[(size_t)(ti * 64 + rr) * 512 + tj * 64 + cc];
        tile[rr][cc] = v;
        W1bf[(size_t)(ti * 64 + rr) * 512 + tj * 64 + cc] = f2b(v);
    }
    __syncthreads();
#pragma unroll
    for (int q = 0; q < 16; ++q) {
        int rr = q * 4 + (t >> 6), cc = t & 63;
        W1T[(size_t)(tj * 64 + rr) * 512 + ti * 64 + cc] = f2b(tile[cc][rr]);
    }
}

// ---------------- c2 = rho(x) @ W2^T + b2 (fp32, exact, once) ----------------
__global__ __launch_bounds__(256) void k_c2(const float* __restrict__ x,
                                            const float* __restrict__ W2,
                                            const float* __restrict__ b2,
                                            float* __restrict__ c2) {
    __shared__ float As[16][68];
    __shared__ float Bs[16][68];
    const int bm = blockIdx.x * 64, bn = blockIdx.y * 64;
    const int tid = threadIdx.x, tx = tid & 15, ty = tid >> 4;
    float acc[4][4] = {};
    for (int k0 = 0; k0 < 784; k0 += 16) {
        const int r = tid >> 4, c = tid & 15;
#pragma unroll
        for (int q = 0; q < 4; ++q) {
            float v = x[(size_t)(bm + r + 16 * q) * 784 + k0 + c];
            As[c][r + 16 * q] = fminf(fmaxf(v, 0.f), 1.f);
        }
#pragma unroll
        for (int q = 0; q < 4; ++q)
            Bs[c][r + 16 * q] = W2[(size_t)(bn + r + 16 * q) * 784 + k0 + c];
        __syncthreads();
#pragma unroll
        for (int k = 0; k < 16; ++k) {
            float a[4], b[4];
#pragma unroll
            for (int i = 0; i < 4; ++i) a[i] = As[k][ty * 4 + i];
#pragma unroll
            for (int j = 0; j < 4; ++j) b[j] = Bs[k][tx * 4 + j];
#pragma unroll
            for (int i = 0; i < 4; ++i)
#pragma unroll
                for (int j = 0; j < 4; ++j) acc[i][j] += a[i] * b[j];
        }
        __syncthreads();
    }
#pragma unroll
    for (int i = 0; i < 4; ++i) {
        int gb = bm + ty * 4 + i;
#pragma unroll
        for (int j = 0; j < 4; ++j) {
            int cl = tx * 4 + j;
            c2[(size_t)gb * 512 + bn + cl] = acc[i][j] + b2[bn + cl];
        }
    }
}

// ---------------- fused step: z1 (256 blocks) + z2 (256 blocks, tn0 also z0) ----------------
// Tile 128x64, K=512, BK=64, MFMA 16x16x32 bf16. LDS K-major, XOR-swizzled 16B units.
__global__ __launch_bounds__(256, 3) void k_step(const ushortT* __restrict__ srcS,
                                                 ushortT* __restrict__ dstS,
                                                 const ushortT* __restrict__ W1bf,
                                                 const ushortT* __restrict__ W1T,
                                                 const float* __restrict__ W0,
                                                 const float* __restrict__ b0,
                                                 const float* __restrict__ b1,
                                                 const float* __restrict__ c2,
                                                 float* __restrict__ outF) {
    __shared__ u32x4 AsR[128 * 8];   // A tile: 128 rows x 64 K (bf16), 8x16B units/row
    __shared__ u32x4 BsR[64 * 8];    // B tile: 64 cols  x 64 K
    __shared__ u32x4 BzR[16 * 8];    // z0 W0 K-major (16-pad cols x 64 K)
    __shared__ u32x4 As2[128 * 4];   // z1 extra-K: s0 (K=32 window, 10 real)
    __shared__ u32x4 Bs2[64 * 4];    // z1 extra-K: W0[k][n]

    const int bid = blockIdx.x;
    const bool isZ1 = bid < 256;
    const int g = isZ1 ? bid : bid - 256;
    const int bm = (g >> 3) * 128;
    const int bn = (g & 7) * 64;
    const bool doZ0 = (!isZ1) && ((g & 7) == 0);
    const int aOff = isZ1 ? OFF2B : OFF1B;            // z1 reads s2, z2 reads s1
    const ushortT* __restrict__ Wb = isZ1 ? W1bf : W1T;

    const int t = threadIdx.x;
    const int lane = t & 63, w = t >> 6;
    const int l15 = lane & 15, l4 = lane >> 4;
    const int mB = (w >> 1) * 64, nB = (w & 1) * 32;  // wave sub-tile 64x32

    f32x4 acc[4][2];
    f32x4 accZ[2];
#pragma unroll
    for (int mi = 0; mi < 4; ++mi)
#pragma unroll
        for (int ni = 0; ni < 2; ++ni) { f32x4 z = {0.f, 0.f, 0.f, 0.f}; acc[mi][ni] = z; }
#pragma unroll
    for (int i = 0; i < 2; ++i) { f32x4 z = {0.f, 0.f, 0.f, 0.f}; accZ[i] = z; }

    const int sr = t >> 1, sh = t & 1;   // A staging: 2 threads/row
    const int bnr = t >> 2, bju = t & 3; // B staging: 4 threads/row

    for (int k0 = 0; k0 < 512; k0 += 64) {
        // ---- stage A (bf16 state rows, 16B-aligned) ----
        const u32x4* gA = (const u32x4*)(srcS + (size_t)(bm + sr) * SPAD + aOff + k0);
#pragma unroll
        for (int j = 0; j < 4; ++j) {
            int u = sh * 4 + j;
            AsR[sr * 8 + (u ^ (sr & 7))] = gA[u];
        }
        // ---- stage B (bf16 weights, row-major K) ----
        const u32x4* gB = (const u32x4*)(Wb + (size_t)(bn + bnr) * 512 + k0);
#pragma unroll
        for (int j = 0; j < 2; ++j) {
            int u = bju * 2 + j;
            BsR[bnr * 8 + (u ^ (bnr & 7))] = gB[u];
        }
        // ---- stage z0 B (W0 fp32 -> bf16, K-major, cols padded to 16) ----
        if (doZ0 && t < 128) {
            int jr = t >> 3, uu = t & 7;
            union { ushortT us[8]; u32x4 v; } pk;
#pragma unroll
            for (int e = 0; e < 8; ++e) pk.us[e] = 0;
            if (jr < 10) {
#pragma unroll
                for (int e = 0; e < 8; ++e) pk.us[e] = f2b(W0[(size_t)jr * 512 + k0 + uu * 8 + e]);
            }
            BzR[jr * 8 + (uu ^ (jr & 7))] = pk.v;
        }
        __syncthreads();
        // ---- compute: 2 K-windows of 32 ----
#pragma unroll
        for (int kw = 0; kw < 2; ++kw) {
            bf16x8 a[4], b[2];
#pragma unroll
            for (int mi = 0; mi < 4; ++mi) {
                int m = mB + mi * 16 + l15;
                a[mi] = __builtin_bit_cast(bf16x8, AsR[m * 8 + ((kw * 4 + l4) ^ (m & 7))]);
            }
#pragma unroll
            for (int ni = 0; ni < 2; ++ni) {
                int n = nB + ni * 16 + l15;
                b[ni] = __builtin_bit_cast(bf16x8, BsR[n * 8 + ((kw * 4 + l4) ^ (n & 7))]);
            }
#pragma unroll
            for (int mi = 0; mi < 4; ++mi)
#pragma unroll
                for (int ni = 0; ni < 2; ++ni)
                    acc[mi][ni] = __builtin_amdgcn_mfma_f32_16x16x32_bf16(a[mi], b[ni], acc[mi][ni], 0, 0, 0);
            if (doZ0) {
                bf16x8 bz = __builtin_bit_cast(bf16x8, BzR[l15 * 8 + ((kw * 4 + l4) ^ (l15 & 7))]);
#pragma unroll
                for (int i = 0; i < 2; ++i)
                    accZ[i] = __builtin_amdgcn_mfma_f32_16x16x32_bf16(a[(w & 1) * 2 + i], bz, accZ[i], 0, 0, 0);
            }
        }
        __syncthreads();
    }

    // ---- z1: one extra zero-padded K=32 window for s0 @ W0 (K=10) ----
    if (isZ1) {
        if (t < 128) {
            union { ushortT us[16]; u32x4 v2[2]; } pk;
#pragma unroll
            for (int e = 0; e < 16; ++e) pk.us[e] = 0;
            const ushortT* sp = srcS + (size_t)(bm + t) * SPAD;
#pragma unroll
            for (int e = 0; e < 10; ++e) pk.us[e] = sp[e];
            u32x4 z = {0u, 0u, 0u, 0u};
            As2[t * 4 + 0] = pk.v2[0];
            As2[t * 4 + 1] = pk.v2[1];
            As2[t * 4 + 2] = z;
            As2[t * 4 + 3] = z;
        } else {
            int idx = t - 128;
            int n = idx >> 1, h = idx & 1;
#pragma unroll
            for (int j = 0; j < 2; ++j) {
                int u = h * 2 + j;
                union { ushortT us[8]; u32x4 v; } pk;
#pragma unroll
                for (int e = 0; e < 8; ++e) {
                    int k = u * 8 + e;
                    pk.us[e] = (k < 10) ? f2b(W0[(size_t)k * 512 + bn + n]) : (ushortT)0;
                }
                Bs2[n * 4 + u] = pk.v;
            }
        }
        __syncthreads();
        {
            bf16x8 a[4], b[2];
#pragma unroll
            for (int mi = 0; mi < 4; ++mi)
                a[mi] = __builtin_bit_cast(bf16x8, As2[(mB + mi * 16 + l15) * 4 + l4]);
#pragma unroll
            for (int ni = 0; ni < 2; ++ni)
                b[ni] = __builtin_bit_cast(bf16x8, Bs2[(nB + ni * 16 + l15) * 4 + l4]);
#pragma unroll
            for (int mi = 0; mi < 4; ++mi)
#pragma unroll
                for (int ni = 0; ni < 2; ++ni)
                    acc[mi][ni] = __builtin_amdgcn_mfma_f32_16x16x32_bf16(a[mi], b[ni], acc[mi][ni], 0, 0, 0);
        }
    }

    // ---- epilogue: n = clip(0.5*old + 0.5*(acc + bias)) ----
    const bool fin = (outF != nullptr);
    if (isZ1) {
#pragma unroll
        for (int ni = 0; ni < 2; ++ni) {
            int gc = bn + nB + ni * 16 + l15;
            float bias = b1[gc];
#pragma unroll
            for (int mi = 0; mi < 4; ++mi) {
#pragma unroll
                for (int q = 0; q < 4; ++q) {
                    size_t gb = (size_t)bm + mB + mi * 16 + l4 * 4 + q;
                    float old = b2f(srcS[gb * SPAD + OFF1B + gc]);
                    float v = 0.5f * old + 0.5f * (acc[mi][ni][q] + bias);
                    v = fminf(fmaxf(v, 0.f), 1.f);
                    if (fin) outF[gb * CSTR + OFF1P + gc] = v;
                    else     dstS[gb * SPAD + OFF1B + gc] = f2b(v);
                }
            }
        }
    } else {
#pragma unroll
        for (int ni = 0; ni < 2; ++ni) {
            int gc = bn + nB + ni * 16 + l15;
#pragma unroll
            for (int mi = 0; mi < 4; ++mi) {
#pragma unroll
                for (int q = 0; q < 4; ++q) {
                    size_t gb = (size_t)bm + mB + mi * 16 + l4 * 4 + q;
                    float bias = c2[gb * 512 + gc];
                    float old = b2f(srcS[gb * SPAD + OFF2B + gc]);
                    float v = 0.5f * old + 0.5f * (acc[mi][ni][q] + bias);
                    v = fminf(fmaxf(v, 0.f), 1.f);
                    if (fin) outF[gb * CSTR + OFF2P + gc] = v;
                    else     dstS[gb * SPAD + OFF2B + gc] = f2b(v);
                }
            }
        }
        if (doZ0 && l15 < 10) {
#pragma unroll
            for (int i = 0; i < 2; ++i) {
#pragma unroll
                for (int q = 0; q < 4; ++q) {
                    size_t gb = (size_t)bm + w * 32 + i * 16 + l4 * 4 + q;
                    float old = b2f(srcS[gb * SPAD + l15]);
                    float v = 0.5f * old + 0.5f * (accZ[i][q] + b0[l15]);
                    v = fminf(fmaxf(v, 0.f), 1.f);
                    if (fin) outF[gb * CSTR + l15] = v;
                    else     dstS[gb * SPAD + l15] = f2b(v);
                }
            }
        }
    }
}

extern "C" void kernel_launch(void* const* d_in, const int* in_sizes, int n_in,
                              void* d_out, int out_size, void* d_ws, size_t ws_size,
                              hipStream_t stream) {
    const float* x  = (const float*)d_in[3];
    const float* W0 = (const float*)d_in[4];
    const float* b0 = (const float*)d_in[5];
    const float* W1 = (const float*)d_in[6];
    const float* b1 = (const float*)d_in[7];
    const float* W2 = (const float*)d_in[8];
    const float* b2 = (const float*)d_in[9];

    // ws layout: sA bf16 [4096*1040] | sB bf16 [4096*1040] | c2 f32 [4096*512]
    //            | W1bf [512*512] | W1T [512*512]   (~26.5 MB total)
    ushortT* sA = (ushortT*)d_ws;
    ushortT* sB = sA + (size_t)BATCH * SPAD;
    float*   c2 = (float*)(sB + (size_t)BATCH * SPAD);
    ushortT* W1bf = (ushortT*)(c2 + (size_t)BATCH * 512);
    ushortT* W1T  = W1bf + 512 * 512;

    const int zeroN = (int)((size_t)BATCH * SPAD * sizeof(ushortT) / sizeof(u32x4));
    k_zero<<<1024, 256, 0, stream>>>((u32x4*)sA, zeroN);
    k_prep<<<64, 256, 0, stream>>>(W1, W1bf, W1T);
    k_c2<<<dim3(64, 8), 256, 0, stream>>>(x, W2, b2, c2);

    for (int tstep = 0; tstep < 30; ++tstep) {
        const ushortT* src = (tstep & 1) ? sB : sA;
        ushortT* dst       = (tstep & 1) ? sA : sB;
        float* outF = (tstep == 29) ? (float*)d_out : nullptr;
        k_step<<<512, 256, 0, stream>>>(src, dst, W1bf, W1T, W0, b0, b1, c2, outF);
    }
}

// Round 4
// 1193.814 us; speedup vs baseline: 2.6172x; 2.6172x over previous
//
#include <hip/hip_runtime.h>

typedef unsigned short ushortT;
typedef short bf16x8 __attribute__((ext_vector_type(8)));
typedef float f32x4 __attribute__((ext_vector_type(4)));
typedef unsigned int u32x4 __attribute__((ext_vector_type(4)));

// EqProp free phase, B=4096, layers [10,512,512 | x=784 clamped], T=30, DT=0.5.
// States stay in [0,1] => rho(s)=s, rhop(s)=1.
// State split hi/lo bf16 (s = hi + lo, ~fp24):
//   hi plane stride 1040: [0,10)=s0 (hi only), [16,528)=s1, [528,1040)=s2
//   lo plane stride 1024: [0,512)=s1_lo, [512,1024)=s2_lo
// Buffer A lives in d_out (zeroed at start = initial state); buffer B in ws.
// Step: n = clip(0.5*s + 0.5*z);  z1 = s2@W1^T + b1 + s0@W0,
//   z2 = c2 + s1@W1 (c2 = rho(x)@W2^T + b2 precomputed), z0 = s1@W0^T + b0.
// Final step (t=29, src=B) writes fp32 packed [4096,1034] into d_out.
#define HSTR 1040
#define LSTR 1024
#define CSTR 1034

__device__ __forceinline__ ushortT f2b(float f) {
    union { float f; unsigned u; } v; v.f = f;
    return (ushortT)((v.u + 0x7FFFu + ((v.u >> 16) & 1u)) >> 16);  // RNE
}
__device__ __forceinline__ float b2f(ushortT b) {
    union { unsigned u; float f; } v; v.u = ((unsigned)b) << 16;
    return v.f;
}
__device__ __forceinline__ void split2(float f, ushortT& h, ushortT& l) {
    h = f2b(f);
    l = f2b(f - b2f(h));
}

#define MFMA(a, b, c) __builtin_amdgcn_mfma_f32_16x16x32_bf16(a, b, c, 0, 0, 0)

// ---------------- zero state buffer A ----------------
__global__ void k_zero(u32x4* __restrict__ p, int n) {
    u32x4 z = {0u, 0u, 0u, 0u};
    for (int i = blockIdx.x * blockDim.x + threadIdx.x; i < n; i += gridDim.x * blockDim.x)
        p[i] = z;
}

// ---------------- W1 -> bf16 row-major + bf16 transpose (proven R2) ----------------
__global__ __launch_bounds__(256) void k_prep(const float* __restrict__ W1,
                                              ushortT* __restrict__ W1bf,
                                              ushortT* __restrict__ W1T) {
    __shared__ float tile[64][65];
    const int ti = blockIdx.x >> 3, tj = blockIdx.x & 7;
    const int t = threadIdx.x;
#pragma unroll
    for (int q = 0; q < 16; ++q) {
        int rr = q * 4 + (t >> 6), cc = t & 63;
        float v = W1[(size_t)(ti * 64 + rr) * 512 + tj * 64 + cc];
        tile[rr][cc] = v;
        W1bf[(size_t)(ti * 64 + rr) * 512 + tj * 64 + cc] = f2b(v);
    }
    __syncthreads();
#pragma unroll
    for (int q = 0; q < 16; ++q) {
        int rr = q * 4 + (t >> 6), cc = t & 63;
        W1T[(size_t)(tj * 64 + rr) * 512 + ti * 64 + cc] = f2b(tile[cc][rr]);
    }
}

// ---------------- c2 = rho(x) @ W2^T + b2 via split-bf16 MFMA (3-pass) ----------------
__global__ __launch_bounds__(256) void k_c2(const float* __restrict__ x,
                                            const float* __restrict__ W2,
                                            const float* __restrict__ b2,
                                            float* __restrict__ c2) {
    __shared__ u32x4 cs[2048];
    u32x4* xHi = cs;          // [64][8]
    u32x4* xLo = cs + 512;
    u32x4* wHi = cs + 1024;
    u32x4* wLo = cs + 1536;
    const int bid = blockIdx.x, t = threadIdx.x;
    const int lane = t & 63, w = t >> 6, l15 = lane & 15, l4 = lane >> 4;
    const int bm2 = (bid >> 3) * 64, bn2 = (bid & 7) * 64;
    const int mB2 = (w >> 1) * 32, nB2 = (w & 1) * 32;
    const int sr2 = t >> 2, ub = (t & 3) * 2;
    f32x4 accC[2][2];
#pragma unroll
    for (int i = 0; i < 2; ++i)
#pragma unroll
        for (int j = 0; j < 2; ++j) { f32x4 z = {0.f, 0.f, 0.f, 0.f}; accC[i][j] = z; }
    for (int k0 = 0; k0 < 784; k0 += 64) {
#pragma unroll
        for (int j = 0; j < 2; ++j) {
            int u = ub + j;
            bool valid = (k0 + u * 8 + 8 <= 784);
            union { ushortT us[8]; u32x4 v; } ph, pl, qh, ql;
            if (valid) {
                const float* srcx = x  + (size_t)(bm2 + sr2) * 784 + k0 + u * 8;
                const float* srcw = W2 + (size_t)(bn2 + sr2) * 784 + k0 + u * 8;
#pragma unroll
                for (int e = 0; e < 8; ++e) {
                    float cx = fminf(fmaxf(srcx[e], 0.f), 1.f);
                    split2(cx, ph.us[e], pl.us[e]);
                    split2(srcw[e], qh.us[e], ql.us[e]);
                }
            } else {
#pragma unroll
                for (int e = 0; e < 8; ++e) { ph.us[e]=0; pl.us[e]=0; qh.us[e]=0; ql.us[e]=0; }
            }
            int sw = u ^ (sr2 & 7);
            xHi[sr2 * 8 + sw] = ph.v;  xLo[sr2 * 8 + sw] = pl.v;
            wHi[sr2 * 8 + sw] = qh.v;  wLo[sr2 * 8 + sw] = ql.v;
        }
        __syncthreads();
        int kwMax = (k0 == 768) ? 1 : 2;
        for (int kw = 0; kw < kwMax; ++kw) {
            bf16x8 ah[2], al[2], bh[2], bl[2];
#pragma unroll
            for (int i = 0; i < 2; ++i) {
                int m = mB2 + i * 16 + l15;
                int uu = (kw * 4 + l4) ^ (m & 7);
                ah[i] = __builtin_bit_cast(bf16x8, xHi[m * 8 + uu]);
                al[i] = __builtin_bit_cast(bf16x8, xLo[m * 8 + uu]);
                int n = nB2 + i * 16 + l15;
                int uv = (kw * 4 + l4) ^ (n & 7);
                bh[i] = __builtin_bit_cast(bf16x8, wHi[n * 8 + uv]);
                bl[i] = __builtin_bit_cast(bf16x8, wLo[n * 8 + uv]);
            }
#pragma unroll
            for (int i = 0; i < 2; ++i)
#pragma unroll
                for (int jj = 0; jj < 2; ++jj) {
                    accC[i][jj] = MFMA(ah[i], bh[jj], accC[i][jj]);
                    accC[i][jj] = MFMA(al[i], bh[jj], accC[i][jj]);
                    accC[i][jj] = MFMA(ah[i], bl[jj], accC[i][jj]);
                }
        }
        __syncthreads();
    }
#pragma unroll
    for (int mi = 0; mi < 2; ++mi)
#pragma unroll
        for (int ni = 0; ni < 2; ++ni)
#pragma unroll
            for (int q = 0; q < 4; ++q) {
                int row = bm2 + mB2 + mi * 16 + l4 * 4 + q;
                int col = bn2 + nB2 + ni * 16 + l15;
                c2[(size_t)row * 512 + col] = accC[mi][ni][q] + b2[col];
            }
}

// ---------------- fused step: z1 (256 blocks) + z2 (256 blocks; bn0 also z0) --------
// XCD-affinity: xcd = bid&7 fixes (role, bm-panel) group; all 8 bn-tiles + the
// producer/consumer of that panel share one XCD's L2.
__global__ __launch_bounds__(256, 2) void k_step(const ushortT* __restrict__ sH,
                                                 const ushortT* __restrict__ sL,
                                                 ushortT* __restrict__ dH,
                                                 ushortT* __restrict__ dL,
                                                 const ushortT* __restrict__ W1bf,
                                                 const ushortT* __restrict__ W1T,
                                                 const float* __restrict__ W0,
                                                 const float* __restrict__ b0,
                                                 const float* __restrict__ b1,
                                                 const float* __restrict__ c2,
                                                 float* __restrict__ outF) {
    __shared__ u32x4 smem[4352];     // 69,632 B -> 2 blocks/CU
    u32x4* AsR = smem;               // 2048: A tile 128 rows x [hi 8u | lo 8u]
    u32x4* BsR = smem + 2048;        //  512: B tile 64 x 8u
    u32x4* Bz0 = smem + 2560;        // 1024: W0^T 16 x 64u (doZ0)
    u32x4* Bs2 = smem + 3584;        //  256: W0 k-window 64 x 4u (z1)
    u32x4* As2 = smem + 3840;        //  512: s0 window 128 x 4u (z1)

    const int bid = blockIdx.x, t = threadIdx.x;
    const int lane = t & 63, w = t >> 6, l15 = lane & 15, l4 = lane >> 4;
    const int mB = w * 32;

    const int xcd = bid & 7, rblk = bid >> 3, bn_i = rblk & 7, grp = rblk >> 3;
    const int pidx = grp * 8 + xcd;          // [0,64): role+panel group
    const bool isZ1 = pidx < 32;
    const int bm = (pidx & 31) * 128, bn = bn_i * 64;
    const bool doZ0 = (!isZ1) && (bn_i == 0);

    // per-launch LDS prep (synced by first in-loop __syncthreads)
    if (isZ1 && t < 64) {   // Bs2: B[n=t][k] = W0[k][bn+t], K window 32 (10 real)
#pragma unroll
        for (int u = 0; u < 4; ++u) {
            union { ushortT us[8]; u32x4 v; } pk;
#pragma unroll
            for (int e = 0; e < 8; ++e) {
                int k = u * 8 + e;
                pk.us[e] = (k < 10) ? f2b(W0[(size_t)k * 512 + bn + t]) : (ushortT)0;
            }
            Bs2[t * 4 + u] = pk.v;
        }
    }
    if (doZ0) {             // Bz0: B[c][k] = W0[c][k], 16 cols x K=512, swizzled
        int c = t >> 4, u0 = (t & 15) * 4;
#pragma unroll
        for (int j = 0; j < 4; ++j) {
            int U = u0 + j;
            union { ushortT us[8]; u32x4 v; } pk;
#pragma unroll
            for (int e = 0; e < 8; ++e)
                pk.us[e] = (c < 10) ? f2b(W0[(size_t)c * 512 + U * 8 + e]) : (ushortT)0;
            Bz0[c * 64 + ((U & ~7) | ((U & 7) ^ (c & 7)))] = pk.v;
        }
    }

    const int aHi = isZ1 ? 528 : 16;     // src panel: z1 reads s2, z2 reads s1
    const int aLo = isZ1 ? 512 : 0;
    const int dHiOff = isZ1 ? 16 : 528;  // dest layer offsets
    const int dLoOff = isZ1 ? 0 : 512;
    const int oOff = isZ1 ? 10 : 522;
    const ushortT* __restrict__ Wb = isZ1 ? W1bf : W1T;
    const int sr = t >> 1, sh = t & 1;
    const int bnr = t >> 2, bju = t & 3;
    const bool fin = (outF != nullptr);

    f32x4 acc[2][4], accZ[2];
#pragma unroll
    for (int mi = 0; mi < 2; ++mi)
#pragma unroll
        for (int ni = 0; ni < 4; ++ni) { f32x4 z = {0.f,0.f,0.f,0.f}; acc[mi][ni] = z; }
#pragma unroll
    for (int i = 0; i < 2; ++i) { f32x4 z = {0.f,0.f,0.f,0.f}; accZ[i] = z; }

    for (int k0 = 0; k0 < 512; k0 += 64) {
        const u32x4* gH = (const u32x4*)(sH + (size_t)(bm + sr) * HSTR + aHi + k0);
        const u32x4* gL = (const u32x4*)(sL + (size_t)(bm + sr) * LSTR + aLo + k0);
#pragma unroll
        for (int j = 0; j < 4; ++j) {
            int u = sh * 4 + j;
            AsR[sr * 16 + (u ^ (sr & 7))] = gH[u];
            AsR[sr * 16 + 8 + (u ^ (sr & 7))] = gL[u];
        }
        const u32x4* gB = (const u32x4*)(Wb + (size_t)(bn + bnr) * 512 + k0);
#pragma unroll
        for (int j = 0; j < 2; ++j) {
            int u = bju * 2 + j;
            BsR[bnr * 8 + (u ^ (bnr & 7))] = gB[u];
        }
        if (isZ1 && k0 == 0 && t < 128) {   // s0 window (hi-only), zero-padded to K=32
            union { ushortT us[16]; u32x4 v2[2]; } pk;
#pragma unroll
            for (int e = 0; e < 16; ++e) pk.us[e] = 0;
            const ushortT* sp = sH + (size_t)(bm + t) * HSTR;
#pragma unroll
            for (int e = 0; e < 10; ++e) pk.us[e] = sp[e];
            u32x4 z = {0u, 0u, 0u, 0u};
            As2[t * 4 + 0] = pk.v2[0];
            As2[t * 4 + 1] = pk.v2[1];
            As2[t * 4 + 2] = z;
            As2[t * 4 + 3] = z;
        }
        __syncthreads();
#pragma unroll
        for (int kw = 0; kw < 2; ++kw) {
            bf16x8 ah[2], al[2], b[4];
#pragma unroll
            for (int mi = 0; mi < 2; ++mi) {
                int m = mB + mi * 16 + l15;
                int u = (kw * 4 + l4) ^ (m & 7);
                ah[mi] = __builtin_bit_cast(bf16x8, AsR[m * 16 + u]);
                al[mi] = __builtin_bit_cast(bf16x8, AsR[m * 16 + 8 + u]);
            }
#pragma unroll
            for (int ni = 0; ni < 4; ++ni) {
                int n = ni * 16 + l15;
                b[ni] = __builtin_bit_cast(bf16x8, BsR[n * 8 + ((kw * 4 + l4) ^ (n & 7))]);
            }
#pragma unroll
            for (int mi = 0; mi < 2; ++mi)
#pragma unroll
                for (int ni = 0; ni < 4; ++ni) {
                    acc[mi][ni] = MFMA(ah[mi], b[ni], acc[mi][ni]);
                    acc[mi][ni] = MFMA(al[mi], b[ni], acc[mi][ni]);
                }
            if (doZ0) {
                int U = (k0 >> 3) + kw * 4 + l4;
                bf16x8 bz = __builtin_bit_cast(bf16x8,
                    Bz0[l15 * 64 + ((U & ~7) | ((U & 7) ^ (l15 & 7)))]);
#pragma unroll
                for (int i = 0; i < 2; ++i) {
                    accZ[i] = MFMA(ah[i], bz, accZ[i]);
                    accZ[i] = MFMA(al[i], bz, accZ[i]);
                }
            }
        }
        __syncthreads();
    }
    if (isZ1) {   // s0 @ W0 extra K window
        bf16x8 a2[2], bb[4];
#pragma unroll
        for (int mi = 0; mi < 2; ++mi)
            a2[mi] = __builtin_bit_cast(bf16x8, As2[(mB + mi * 16 + l15) * 4 + l4]);
#pragma unroll
        for (int ni = 0; ni < 4; ++ni)
            bb[ni] = __builtin_bit_cast(bf16x8, Bs2[(ni * 16 + l15) * 4 + l4]);
#pragma unroll
        for (int mi = 0; mi < 2; ++mi)
#pragma unroll
            for (int ni = 0; ni < 4; ++ni)
                acc[mi][ni] = MFMA(a2[mi], bb[ni], acc[mi][ni]);
    }

    // epilogue: v = clip(0.5*old + 0.5*(acc + bias))
#pragma unroll
    for (int ni = 0; ni < 4; ++ni) {
        int gc = bn + ni * 16 + l15;
        float biasN = isZ1 ? b1[gc] : 0.f;
#pragma unroll
        for (int mi = 0; mi < 2; ++mi) {
#pragma unroll
            for (int q = 0; q < 4; ++q) {
                size_t gb = (size_t)bm + mB + mi * 16 + l4 * 4 + q;
                float bias = isZ1 ? biasN : c2[gb * 512 + gc];
                float old = b2f(sH[gb * HSTR + dHiOff + gc]) + b2f(sL[gb * LSTR + dLoOff + gc]);
                float v = 0.5f * old + 0.5f * (acc[mi][ni][q] + bias);
                v = fminf(fmaxf(v, 0.f), 1.f);
                if (fin) {
                    outF[gb * CSTR + oOff + gc] = v;
                } else {
                    ushortT hh, ll;
                    split2(v, hh, ll);
                    dH[gb * HSTR + dHiOff + gc] = hh;
                    dL[gb * LSTR + dLoOff + gc] = ll;
                }
            }
        }
    }
    if (doZ0 && l15 < 10) {
        float b0v = b0[l15];
#pragma unroll
        for (int i = 0; i < 2; ++i) {
#pragma unroll
            for (int q = 0; q < 4; ++q) {
                size_t gb = (size_t)bm + w * 32 + i * 16 + l4 * 4 + q;
                float old = b2f(sH[gb * HSTR + l15]);
                float v = 0.5f * old + 0.5f * (accZ[i][q] + b0v);
                v = fminf(fmaxf(v, 0.f), 1.f);
                if (fin) outF[gb * CSTR + l15] = v;
                else     dH[gb * HSTR + l15] = f2b(v);
            }
        }
    }
}

extern "C" void kernel_launch(void* const* d_in, const int* in_sizes, int n_in,
                              void* d_out, int out_size, void* d_ws, size_t ws_size,
                              hipStream_t stream) {
    const float* x  = (const float*)d_in[3];
    const float* W0 = (const float*)d_in[4];
    const float* b0 = (const float*)d_in[5];
    const float* W1 = (const float*)d_in[6];
    const float* b1 = (const float*)d_in[7];
    const float* W2 = (const float*)d_in[8];
    const float* b2 = (const float*)d_in[9];

    // buffer A (hi+lo) in d_out: 4096*(1040+1024)*2 = 16,908,288 B <= 16,943,104 B
    ushortT* hiA = (ushortT*)d_out;
    ushortT* loA = hiA + (size_t)4096 * HSTR;
    // ws: hiB | loB | c2 f32 | W1bf | W1T   (~26.3 MB, <= R2-proven 26.5 MB)
    ushortT* hiB = (ushortT*)d_ws;
    ushortT* loB = hiB + (size_t)4096 * HSTR;
    float*   c2  = (float*)(loB + (size_t)4096 * LSTR);
    ushortT* W1bf = (ushortT*)(c2 + (size_t)4096 * 512);
    ushortT* W1T  = W1bf + 512 * 512;

    const int zeroN = (int)((size_t)4096 * (HSTR + LSTR) * sizeof(ushortT) / sizeof(u32x4));
    k_zero<<<1024, 256, 0, stream>>>((u32x4*)d_out, zeroN);
    k_prep<<<64, 256, 0, stream>>>(W1, W1bf, W1T);
    k_c2<<<512, 256, 0, stream>>>(x, W2, b2, c2);

    for (int ts = 0; ts < 30; ++ts) {
        const ushortT* sH = (ts & 1) ? hiB : hiA;
        const ushortT* sL = (ts & 1) ? loB : loA;
        ushortT* dH = (ts & 1) ? hiA : hiB;
        ushortT* dL = (ts & 1) ? loA : loB;
        float* outF = (ts == 29) ? (float*)d_out : nullptr;
        k_step<<<512, 256, 0, stream>>>(sH, sL, dH, dL, W1bf, W1T, W0, b0, b1, c2, outF);
    }
}

// Round 6
// 813.747 us; speedup vs baseline: 3.8395x; 1.4671x over previous
//
#include <hip/hip_runtime.h>

typedef unsigned short ushortT;
typedef short bf16x8 __attribute__((ext_vector_type(8)));
typedef float f32x4 __attribute__((ext_vector_type(4)));
typedef unsigned int u32x4 __attribute__((ext_vector_type(4)));

// EqProp free phase, B=4096, layers [10,512,512 | x=784 clamped], T=30, DT=0.5.
// States stay in [0,1] => rho(s)=s, rhop(s)=1.
// State: SINGLE bf16 plane, row stride 1056 (2112 B, 64B-aligned rows):
//   [0,10)=s0, [32,544)=s1, [544,1056)=s2   (offsets 64B-aligned)
// Weights W1 split hi/lo bf16 (W1 ~ Wh + Wl, fp24-accurate) -> weight-quant error killed.
// Step: n = clip(0.5*s + 0.5*z);  z1 = s2@W1^T + b1 + s0@W0,
//   z2 = c2 + s1@W1 (c2 = rho(x)@W2^T + b2, fp32, precomputed), z0 = s1@W0^T + b0.
// Final step (t=29) writes fp32 packed [4096,1034] into d_out.
#define HSTR 1056
#define OFF1B 32
#define OFF2B 544
#define CSTR 1034

__device__ __forceinline__ ushortT f2b(float f) {
    union { float f; unsigned u; } v; v.f = f;
    return (ushortT)((v.u + 0x7FFFu + ((v.u >> 16) & 1u)) >> 16);  // RNE
}
__device__ __forceinline__ float b2f(ushortT b) {
    union { unsigned u; float f; } v; v.u = ((unsigned)b) << 16;
    return v.f;
}
__device__ __forceinline__ void split2(float f, ushortT& h, ushortT& l) {
    h = f2b(f);
    l = f2b(f - b2f(h));
}

#define MFMA(a, b, c) __builtin_amdgcn_mfma_f32_16x16x32_bf16(a, b, c, 0, 0, 0)
#define BCAST(x) __builtin_bit_cast(bf16x8, x)

// ---------------- zero state buffer A ----------------
__global__ void k_zero(u32x4* __restrict__ p, int n) {
    u32x4 z = {0u, 0u, 0u, 0u};
    for (int i = blockIdx.x * blockDim.x + threadIdx.x; i < n; i += gridDim.x * blockDim.x)
        p[i] = z;
}

// ---------------- W1 -> split bf16 hi/lo, row-major + transpose ----------------
__global__ __launch_bounds__(256) void k_prep(const float* __restrict__ W1,
                                              ushortT* __restrict__ W1h,
                                              ushortT* __restrict__ W1l,
                                              ushortT* __restrict__ W1Th,
                                              ushortT* __restrict__ W1Tl) {
    __shared__ float tile[64][65];
    const int ti = blockIdx.x >> 3, tj = blockIdx.x & 7;
    const int t = threadIdx.x;
#pragma unroll
    for (int q = 0; q < 16; ++q) {
        int rr = q * 4 + (t >> 6), cc = t & 63;
        float v = W1[(size_t)(ti * 64 + rr) * 512 + tj * 64 + cc];
        tile[rr][cc] = v;
        ushortT h, l; split2(v, h, l);
        W1h[(size_t)(ti * 64 + rr) * 512 + tj * 64 + cc] = h;
        W1l[(size_t)(ti * 64 + rr) * 512 + tj * 64 + cc] = l;
    }
    __syncthreads();
#pragma unroll
    for (int q = 0; q < 16; ++q) {
        int rr = q * 4 + (t >> 6), cc = t & 63;
        ushortT h, l; split2(tile[cc][rr], h, l);
        W1Th[(size_t)(tj * 64 + rr) * 512 + ti * 64 + cc] = h;
        W1Tl[(size_t)(tj * 64 + rr) * 512 + ti * 64 + cc] = l;
    }
}

// ---------------- c2 = rho(x) @ W2^T + b2 via split-bf16 MFMA (3-pass, proven R4) ----
__global__ __launch_bounds__(256) void k_c2(const float* __restrict__ x,
                                            const float* __restrict__ W2,
                                            const float* __restrict__ b2,
                                            float* __restrict__ c2) {
    __shared__ u32x4 cs[2048];
    u32x4* xHi = cs;
    u32x4* xLo = cs + 512;
    u32x4* wHi = cs + 1024;
    u32x4* wLo = cs + 1536;
    const int bid = blockIdx.x, t = threadIdx.x;
    const int lane = t & 63, w = t >> 6, l15 = lane & 15, l4 = lane >> 4;
    const int bm2 = (bid >> 3) * 64, bn2 = (bid & 7) * 64;
    const int mB2 = (w >> 1) * 32, nB2 = (w & 1) * 32;
    const int sr2 = t >> 2, ub = (t & 3) * 2;
    f32x4 accC[2][2];
#pragma unroll
    for (int i = 0; i < 2; ++i)
#pragma unroll
        for (int j = 0; j < 2; ++j) { f32x4 z = {0.f, 0.f, 0.f, 0.f}; accC[i][j] = z; }
    for (int k0 = 0; k0 < 784; k0 += 64) {
#pragma unroll
        for (int j = 0; j < 2; ++j) {
            int u = ub + j;
            bool valid = (k0 + u * 8 + 8 <= 784);
            union { ushortT us[8]; u32x4 v; } ph, pl, qh, ql;
            if (valid) {
                const float* srcx = x  + (size_t)(bm2 + sr2) * 784 + k0 + u * 8;
                const float* srcw = W2 + (size_t)(bn2 + sr2) * 784 + k0 + u * 8;
#pragma unroll
                for (int e = 0; e < 8; ++e) {
                    float cx = fminf(fmaxf(srcx[e], 0.f), 1.f);
                    split2(cx, ph.us[e], pl.us[e]);
                    split2(srcw[e], qh.us[e], ql.us[e]);
                }
            } else {
#pragma unroll
                for (int e = 0; e < 8; ++e) { ph.us[e]=0; pl.us[e]=0; qh.us[e]=0; ql.us[e]=0; }
            }
            int sw = u ^ (sr2 & 7);
            xHi[sr2 * 8 + sw] = ph.v;  xLo[sr2 * 8 + sw] = pl.v;
            wHi[sr2 * 8 + sw] = qh.v;  wLo[sr2 * 8 + sw] = ql.v;
        }
        __syncthreads();
        int kwMax = (k0 == 768) ? 1 : 2;
        for (int kw = 0; kw < kwMax; ++kw) {
            bf16x8 ah[2], al[2], bh[2], bl[2];
#pragma unroll
            for (int i = 0; i < 2; ++i) {
                int m = mB2 + i * 16 + l15;
                int uu = (kw * 4 + l4) ^ (m & 7);
                ah[i] = BCAST(xHi[m * 8 + uu]);
                al[i] = BCAST(xLo[m * 8 + uu]);
                int n = nB2 + i * 16 + l15;
                int uv = (kw * 4 + l4) ^ (n & 7);
                bh[i] = BCAST(wHi[n * 8 + uv]);
                bl[i] = BCAST(wLo[n * 8 + uv]);
            }
#pragma unroll
            for (int i = 0; i < 2; ++i)
#pragma unroll
                for (int jj = 0; jj < 2; ++jj) {
                    accC[i][jj] = MFMA(ah[i], bh[jj], accC[i][jj]);
                    accC[i][jj] = MFMA(al[i], bh[jj], accC[i][jj]);
                    accC[i][jj] = MFMA(ah[i], bl[jj], accC[i][jj]);
                }
        }
        __syncthreads();
    }
#pragma unroll
    for (int mi = 0; mi < 2; ++mi)
#pragma unroll
        for (int ni = 0; ni < 2; ++ni)
#pragma unroll
            for (int q = 0; q < 4; ++q) {
                int row = bm2 + mB2 + mi * 16 + l4 * 4 + q;
                int col = bn2 + nB2 + ni * 16 + l15;
                c2[(size_t)row * 512 + col] = accC[mi][ni][q] + b2[col];
            }
}

// ---------------- fused step: z1 (256 blocks) + z2 (256 blocks; bn0 also z0) --------
// XCD-affinity: xcd = bid&7; producer/consumers of each 128-row panel share one XCD.
__global__ __launch_bounds__(256, 3) void k_step(const ushortT* __restrict__ sH,
                                                 ushortT* __restrict__ dH,
                                                 const ushortT* __restrict__ W1h,
                                                 const ushortT* __restrict__ W1l,
                                                 const ushortT* __restrict__ W1Th,
                                                 const ushortT* __restrict__ W1Tl,
                                                 const float* __restrict__ W0,
                                                 const float* __restrict__ b0,
                                                 const float* __restrict__ b1,
                                                 const float* __restrict__ c2,
                                                 float* __restrict__ outF) {
    __shared__ u32x4 smem[3072];     // 48 KiB -> 3 blocks/CU
    u32x4* AsR = smem;               // 1024: A tile [128 rows][8 units], swizzled
    u32x4* BhS = smem + 1024;        //  512: W-hi tile [64][8]
    u32x4* BlS = smem + 1536;        //  512: W-lo tile [64][8]
    u32x4* aux = smem + 2048;        // 1024: overlay: doZ0 -> Bz0[16][64]; z1 -> Bs2[64][4] + As2[128][4]

    const int bid = blockIdx.x, t = threadIdx.x;
    const int lane = t & 63, w = t >> 6, l15 = lane & 15, l4 = lane >> 4;
    const int mB = w * 32;

    const int xcd = bid & 7, rblk = bid >> 3, bn_i = rblk & 7, grp = rblk >> 3;
    const int pidx = grp * 8 + xcd;
    const bool isZ1 = pidx < 32;
    const int bm = (pidx & 31) * 128, bn = bn_i * 64;
    const bool doZ0 = (!isZ1) && (bn_i == 0);

    // ---- aux LDS staging (published by the pipeline's first publish-barrier) ----
    if (isZ1) {
        if (t < 64) {   // Bs2[n][u]: B[n][k] = W0[k][bn+n], K window 32 (10 real)
#pragma unroll
            for (int u = 0; u < 4; ++u) {
                union { ushortT us[8]; u32x4 v; } pk;
#pragma unroll
                for (int e = 0; e < 8; ++e) {
                    int k = u * 8 + e;
                    pk.us[e] = (k < 10) ? f2b(W0[(size_t)k * 512 + bn + t]) : (ushortT)0;
                }
                aux[t * 4 + u] = pk.v;
            }
        }
        if (t < 128) {  // As2[row][u]: s0 window, zero-padded to K=32
            union { ushortT us[16]; u32x4 v2[2]; } pk;
#pragma unroll
            for (int e = 0; e < 16; ++e) pk.us[e] = 0;
            const ushortT* sp = sH + (size_t)(bm + t) * HSTR;
#pragma unroll
            for (int e = 0; e < 10; ++e) pk.us[e] = sp[e];
            u32x4 z = {0u, 0u, 0u, 0u};
            aux[256 + t * 4 + 0] = pk.v2[0];
            aux[256 + t * 4 + 1] = pk.v2[1];
            aux[256 + t * 4 + 2] = z;
            aux[256 + t * 4 + 3] = z;
        }
    } else if (doZ0) {  // Bz0[c][64 units]: W0^T, 16 cols x K=512, swizzled
        int c = t >> 4, u0 = (t & 15) * 4;
#pragma unroll
        for (int j = 0; j < 4; ++j) {
            int U = u0 + j;
            union { ushortT us[8]; u32x4 v; } pk;
#pragma unroll
            for (int e = 0; e < 8; ++e)
                pk.us[e] = (c < 10) ? f2b(W0[(size_t)c * 512 + U * 8 + e]) : (ushortT)0;
            aux[c * 64 + ((U & ~7) | ((U & 7) ^ (c & 7)))] = pk.v;
        }
    }

    const int aOff = isZ1 ? OFF2B : OFF1B;   // src panel: z1 reads s2, z2 reads s1
    const int dOff = isZ1 ? OFF1B : OFF2B;   // dest layer
    const int oOff = isZ1 ? 10 : 522;
    const ushortT* __restrict__ Wbh = isZ1 ? W1h : W1Th;
    const ushortT* __restrict__ Wbl = isZ1 ? W1l : W1Tl;
    const int sr = t >> 1, sh = t & 1;       // A staging: 2 thr/row, 4 units each
    const int bnr = t >> 2, bju = t & 3;     // B staging: 4 thr/row, 2 units each
    const bool fin = (outF != nullptr);

    f32x4 acc[2][4], accZ[2];
#pragma unroll
    for (int mi = 0; mi < 2; ++mi)
#pragma unroll
        for (int ni = 0; ni < 4; ++ni) { f32x4 z = {0.f,0.f,0.f,0.f}; acc[mi][ni] = z; }
#pragma unroll
    for (int i = 0; i < 2; ++i) { f32x4 z = {0.f,0.f,0.f,0.f}; accZ[i] = z; }

    // ---- software-pipelined K loop: reg-staged double buffer ----
    u32x4 rA[2][4], rBh[2][2], rBl[2][2];
    {
        const u32x4* gA = (const u32x4*)(sH + (size_t)(bm + sr) * HSTR + aOff);
        const u32x4* gh = (const u32x4*)(Wbh + (size_t)(bn + bnr) * 512);
        const u32x4* gl = (const u32x4*)(Wbl + (size_t)(bn + bnr) * 512);
#pragma unroll
        for (int j = 0; j < 4; ++j) rA[0][j] = gA[sh * 4 + j];
#pragma unroll
        for (int j = 0; j < 2; ++j) { rBh[0][j] = gh[bju * 2 + j]; rBl[0][j] = gl[bju * 2 + j]; }
    }
#pragma unroll
    for (int it = 0; it < 8; ++it) {
        const int k0 = it * 64;
        const int cur = it & 1, nxt = cur ^ 1;
        __syncthreads();                      // prev compute done; LDS reusable
#pragma unroll
        for (int j = 0; j < 4; ++j) {
            int u = sh * 4 + j;
            AsR[sr * 8 + (u ^ (sr & 7))] = rA[cur][j];
        }
#pragma unroll
        for (int j = 0; j < 2; ++j) {
            int u = bju * 2 + j;
            BhS[bnr * 8 + (u ^ (bnr & 7))] = rBh[cur][j];
            BlS[bnr * 8 + (u ^ (bnr & 7))] = rBl[cur][j];
        }
        if (it < 7) {                         // prefetch next K tile into regs
            const int k1 = k0 + 64;
            const u32x4* gA = (const u32x4*)(sH + (size_t)(bm + sr) * HSTR + aOff + k1);
            const u32x4* gh = (const u32x4*)(Wbh + (size_t)(bn + bnr) * 512 + k1);
            const u32x4* gl = (const u32x4*)(Wbl + (size_t)(bn + bnr) * 512 + k1);
#pragma unroll
            for (int j = 0; j < 4; ++j) rA[nxt][j] = gA[sh * 4 + j];
#pragma unroll
            for (int j = 0; j < 2; ++j) { rBh[nxt][j] = gh[bju * 2 + j]; rBl[nxt][j] = gl[bju * 2 + j]; }
        }
        __syncthreads();                      // publish LDS
#pragma unroll
        for (int kw = 0; kw < 2; ++kw) {
            bf16x8 a[2], bh[4], bl[4];
#pragma unroll
            for (int mi = 0; mi < 2; ++mi) {
                int m = mB + mi * 16 + l15;
                a[mi] = BCAST(AsR[m * 8 + ((kw * 4 + l4) ^ (m & 7))]);
            }
#pragma unroll
            for (int ni = 0; ni < 4; ++ni) {
                int n = ni * 16 + l15;
                int u = (kw * 4 + l4) ^ (n & 7);
                bh[ni] = BCAST(BhS[n * 8 + u]);
                bl[ni] = BCAST(BlS[n * 8 + u]);
            }
#pragma unroll
            for (int mi = 0; mi < 2; ++mi)
#pragma unroll
                for (int ni = 0; ni < 4; ++ni) {
                    acc[mi][ni] = MFMA(a[mi], bh[ni], acc[mi][ni]);
                    acc[mi][ni] = MFMA(a[mi], bl[ni], acc[mi][ni]);
                }
            if (doZ0) {
                int U = (k0 >> 3) + kw * 4 + l4;
                bf16x8 bz = BCAST(aux[l15 * 64 + ((U & ~7) | ((U & 7) ^ (l15 & 7)))]);
                accZ[0] = MFMA(a[0], bz, accZ[0]);
                accZ[1] = MFMA(a[1], bz, accZ[1]);
            }
        }
    }
    if (isZ1) {   // s0 @ W0 extra K window
        bf16x8 a2[2], bb[4];
#pragma unroll
        for (int mi = 0; mi < 2; ++mi)
            a2[mi] = BCAST(aux[256 + (mB + mi * 16 + l15) * 4 + l4]);
#pragma unroll
        for (int ni = 0; ni < 4; ++ni)
            bb[ni] = BCAST(aux[(ni * 16 + l15) * 4 + l4]);
#pragma unroll
        for (int mi = 0; mi < 2; ++mi)
#pragma unroll
            for (int ni = 0; ni < 4; ++ni)
                acc[mi][ni] = MFMA(a2[mi], bb[ni], acc[mi][ni]);
    }

    // ---- epilogue: v = clip(0.5*old + 0.5*(acc + bias)) ----
    __syncthreads();   // all LDS reads done; AsR reusable as output staging
    if (fin) {
#pragma unroll
        for (int ni = 0; ni < 4; ++ni) {
            int gc = bn + ni * 16 + l15;
            float biasN = isZ1 ? b1[gc] : 0.f;
#pragma unroll
            for (int mi = 0; mi < 2; ++mi) {
#pragma unroll
                for (int q = 0; q < 4; ++q) {
                    size_t gb = (size_t)bm + mB + mi * 16 + l4 * 4 + q;
                    float bias = isZ1 ? biasN : c2[gb * 512 + gc];
                    float old = b2f(sH[gb * HSTR + dOff + gc]);
                    float v = 0.5f * old + 0.5f * (acc[mi][ni][q] + bias);
                    v = fminf(fmaxf(v, 0.f), 1.f);
                    outF[gb * CSTR + oOff + gc] = v;
                }
            }
        }
        if (doZ0 && l15 < 10) {
            float b0v = b0[l15];
#pragma unroll
            for (int i = 0; i < 2; ++i) {
#pragma unroll
                for (int q = 0; q < 4; ++q) {
                    size_t gb = (size_t)bm + w * 32 + i * 16 + l4 * 4 + q;
                    float old = b2f(sH[gb * HSTR + l15]);
                    float v = 0.5f * old + 0.5f * (accZ[i][q] + b0v);
                    v = fminf(fmaxf(v, 0.f), 1.f);
                    outF[gb * CSTR + l15] = v;
                }
            }
        }
    } else {
        ushortT* dlds = (ushortT*)AsR;   // 128x64 bf16 output tile, linear
#pragma unroll
        for (int ni = 0; ni < 4; ++ni) {
            int gc = bn + ni * 16 + l15;
            float biasN = isZ1 ? b1[gc] : 0.f;
#pragma unroll
            for (int mi = 0; mi < 2; ++mi) {
#pragma unroll
                for (int q = 0; q < 4; ++q) {
                    size_t gb = (size_t)bm + mB + mi * 16 + l4 * 4 + q;
                    float bias = isZ1 ? biasN : c2[gb * 512 + gc];
                    float old = b2f(sH[gb * HSTR + dOff + gc]);
                    float v = 0.5f * old + 0.5f * (acc[mi][ni][q] + bias);
                    v = fminf(fmaxf(v, 0.f), 1.f);
                    dlds[(mB + mi * 16 + l4 * 4 + q) * 64 + ni * 16 + l15] = f2b(v);
                }
            }
        }
        if (doZ0 && l15 < 10) {
            float b0v = b0[l15];
#pragma unroll
            for (int i = 0; i < 2; ++i) {
#pragma unroll
                for (int q = 0; q < 4; ++q) {
                    size_t gb = (size_t)bm + w * 32 + i * 16 + l4 * 4 + q;
                    float old = b2f(sH[gb * HSTR + l15]);
                    float v = 0.5f * old + 0.5f * (accZ[i][q] + b0v);
                    v = fminf(fmaxf(v, 0.f), 1.f);
                    dH[gb * HSTR + l15] = f2b(v);
                }
            }
        }
        __syncthreads();
        // coalesced 16B-per-lane tile store into THIS block's column slice
        // (bug fixed: was missing "+ bn" -> all bn-tiles overwrote cols [dOff,dOff+64))
#pragma unroll
        for (int j = 0; j < 4; ++j) {
            int i = j * 256 + t;
            int row = i >> 3, u = i & 7;
            ((u32x4*)(dH + (size_t)(bm + row) * HSTR + dOff + bn))[u] = AsR[i];
        }
    }
}

extern "C" void kernel_launch(void* const* d_in, const int* in_sizes, int n_in,
                              void* d_out, int out_size, void* d_ws, size_t ws_size,
                              hipStream_t stream) {
    const float* x  = (const float*)d_in[3];
    const float* W0 = (const float*)d_in[4];
    const float* b0 = (const float*)d_in[5];
    const float* W1 = (const float*)d_in[6];
    const float* b1 = (const float*)d_in[7];
    const float* W2 = (const float*)d_in[8];
    const float* b2 = (const float*)d_in[9];

    // buffer A in d_out: 4096*1056*2 = 8,650,752 B <= 16,943,104 B
    ushortT* hiA = (ushortT*)d_out;
    // ws: hiB | c2 f32 | W1h | W1l | W1Th | W1Tl   (~19.1 MB)
    ushortT* hiB = (ushortT*)d_ws;
    float*   c2  = (float*)(hiB + (size_t)4096 * HSTR);
    ushortT* W1h = (ushortT*)(c2 + (size_t)4096 * 512);
    ushortT* W1l  = W1h + 512 * 512;
    ushortT* W1Th = W1l + 512 * 512;
    ushortT* W1Tl = W1Th + 512 * 512;

    const int zeroN = (int)((size_t)4096 * HSTR * sizeof(ushortT) / sizeof(u32x4));
    k_zero<<<1024, 256, 0, stream>>>((u32x4*)hiA, zeroN);
    k_prep<<<64, 256, 0, stream>>>(W1, W1h, W1l, W1Th, W1Tl);
    k_c2<<<512, 256, 0, stream>>>(x, W2, b2, c2);

    for (int ts = 0; ts < 30; ++ts) {
        const ushortT* sH = (ts & 1) ? hiB : hiA;
        ushortT* dH       = (ts & 1) ? hiA : hiB;
        float* outF = (ts == 29) ? (float*)d_out : nullptr;
        k_step<<<512, 256, 0, stream>>>(sH, dH, W1h, W1l, W1Th, W1Tl, W0, b0, b1, c2, outF);
    }
}

// Round 7
// 811.961 us; speedup vs baseline: 3.8480x; 1.0022x over previous
//
#include <hip/hip_runtime.h>

typedef unsigned short ushortT;
typedef short bf16x8 __attribute__((ext_vector_type(8)));
typedef float f32x4 __attribute__((ext_vector_type(4)));
typedef unsigned int u32x4 __attribute__((ext_vector_type(4)));

// EqProp free phase, B=4096, layers [10,512,512 | x=784 clamped], T=30, DT=0.5.
// States stay in [0,1] => rho(s)=s, rhop(s)=1.
// State: SINGLE bf16 plane, row stride 1056 (2112 B, 64B-aligned rows):
//   [0,10)=s0, [32,544)=s1, [544,1056)=s2
// Weights W1 split hi/lo bf16 (W1 ~ Wh + Wl) -> weight-quant error killed.
// Step: n = clip(0.5*s + 0.5*z);  z1 = s2@W1^T + b1 + s0@W0,
//   z2 = c2 + s1@W1 (c2 = rho(x)@W2^T + b2, fp32, precomputed), z0 = s1@W0^T + b0.
// Persistent kernel: c2 tile and each block's own previous output tile live in
// REGISTERS across all 30 steps (grid barrier between steps). Fallback: 30
// per-step launches (proven R6 path) if occupancy guard fails.
#define HSTR 1056
#define OFF1B 32
#define OFF2B 544
#define CSTR 1034
#define NBLK 512

__device__ __forceinline__ ushortT f2b(float f) {
    union { float f; unsigned u; } v; v.f = f;
    return (ushortT)((v.u + 0x7FFFu + ((v.u >> 16) & 1u)) >> 16);  // RNE
}
__device__ __forceinline__ float b2f(ushortT b) {
    union { unsigned u; float f; } v; v.u = ((unsigned)b) << 16;
    return v.f;
}
__device__ __forceinline__ void split2(float f, ushortT& h, ushortT& l) {
    h = f2b(f);
    l = f2b(f - b2f(h));
}

#define MFMA(a, b, c) __builtin_amdgcn_mfma_f32_16x16x32_bf16(a, b, c, 0, 0, 0)
#define BCAST(x) __builtin_bit_cast(bf16x8, x)

// sense-reversing grid barrier; bar[0]=count, bar[1]=generation (zeroed per call)
__device__ __forceinline__ void grid_barrier(unsigned* bar) {
    __syncthreads();
    if (threadIdx.x == 0) {
        __threadfence();   // release: flush this XCD's dirty lines device-wide
        unsigned g = __hip_atomic_load(bar + 1, __ATOMIC_RELAXED, __HIP_MEMORY_SCOPE_AGENT);
        unsigned a = __hip_atomic_fetch_add(bar, 1u, __ATOMIC_ACQ_REL, __HIP_MEMORY_SCOPE_AGENT);
        if (a == NBLK - 1u) {
            __hip_atomic_store(bar, 0u, __ATOMIC_RELAXED, __HIP_MEMORY_SCOPE_AGENT);
            __hip_atomic_fetch_add(bar + 1, 1u, __ATOMIC_RELEASE, __HIP_MEMORY_SCOPE_AGENT);
        } else {
            while (__hip_atomic_load(bar + 1, __ATOMIC_ACQUIRE, __HIP_MEMORY_SCOPE_AGENT) == g)
                __builtin_amdgcn_s_sleep(2);
        }
        __threadfence();   // acquire: invalidate stale lines
    }
    __syncthreads();
}

// ---------------- zero state buffer A + barrier words ----------------
__global__ void k_zero(u32x4* __restrict__ p, int n, unsigned* __restrict__ bar) {
    u32x4 z = {0u, 0u, 0u, 0u};
    for (int i = blockIdx.x * blockDim.x + threadIdx.x; i < n; i += gridDim.x * blockDim.x)
        p[i] = z;
    if (blockIdx.x == 0 && threadIdx.x == 0) { bar[0] = 0u; bar[1] = 0u; }
}

// ---------------- W1 -> split bf16 hi/lo, row-major + transpose ----------------
__global__ __launch_bounds__(256) void k_prep(const float* __restrict__ W1,
                                              ushortT* __restrict__ W1h,
                                              ushortT* __restrict__ W1l,
                                              ushortT* __restrict__ W1Th,
                                              ushortT* __restrict__ W1Tl) {
    __shared__ float tile[64][65];
    const int ti = blockIdx.x >> 3, tj = blockIdx.x & 7;
    const int t = threadIdx.x;
#pragma unroll
    for (int q = 0; q < 16; ++q) {
        int rr = q * 4 + (t >> 6), cc = t & 63;
        float v = W1[(size_t)(ti * 64 + rr) * 512 + tj * 64 + cc];
        tile[rr][cc] = v;
        ushortT h, l; split2(v, h, l);
        W1h[(size_t)(ti * 64 + rr) * 512 + tj * 64 + cc] = h;
        W1l[(size_t)(ti * 64 + rr) * 512 + tj * 64 + cc] = l;
    }
    __syncthreads();
#pragma unroll
    for (int q = 0; q < 16; ++q) {
        int rr = q * 4 + (t >> 6), cc = t & 63;
        ushortT h, l; split2(tile[cc][rr], h, l);
        W1Th[(size_t)(tj * 64 + rr) * 512 + ti * 64 + cc] = h;
        W1Tl[(size_t)(tj * 64 + rr) * 512 + ti * 64 + cc] = l;
    }
}

// ---------------- c2 = rho(x) @ W2^T + b2 via split-bf16 MFMA (3-pass) ----------------
__global__ __launch_bounds__(256) void k_c2(const float* __restrict__ x,
                                            const float* __restrict__ W2,
                                            const float* __restrict__ b2,
                                            float* __restrict__ c2) {
    __shared__ u32x4 cs[2048];
    u32x4* xHi = cs;
    u32x4* xLo = cs + 512;
    u32x4* wHi = cs + 1024;
    u32x4* wLo = cs + 1536;
    const int bid = blockIdx.x, t = threadIdx.x;
    const int lane = t & 63, w = t >> 6, l15 = lane & 15, l4 = lane >> 4;
    const int bm2 = (bid >> 3) * 64, bn2 = (bid & 7) * 64;
    const int mB2 = (w >> 1) * 32, nB2 = (w & 1) * 32;
    const int sr2 = t >> 2, ub = (t & 3) * 2;
    f32x4 accC[2][2];
#pragma unroll
    for (int i = 0; i < 2; ++i)
#pragma unroll
        for (int j = 0; j < 2; ++j) { f32x4 z = {0.f, 0.f, 0.f, 0.f}; accC[i][j] = z; }
    for (int k0 = 0; k0 < 784; k0 += 64) {
#pragma unroll
        for (int j = 0; j < 2; ++j) {
            int u = ub + j;
            bool valid = (k0 + u * 8 + 8 <= 784);
            union { ushortT us[8]; u32x4 v; } ph, pl, qh, ql;
            if (valid) {
                const float* srcx = x  + (size_t)(bm2 + sr2) * 784 + k0 + u * 8;
                const float* srcw = W2 + (size_t)(bn2 + sr2) * 784 + k0 + u * 8;
#pragma unroll
                for (int e = 0; e < 8; ++e) {
                    float cx = fminf(fmaxf(srcx[e], 0.f), 1.f);
                    split2(cx, ph.us[e], pl.us[e]);
                    split2(srcw[e], qh.us[e], ql.us[e]);
                }
            } else {
#pragma unroll
                for (int e = 0; e < 8; ++e) { ph.us[e]=0; pl.us[e]=0; qh.us[e]=0; ql.us[e]=0; }
            }
            int sw = u ^ (sr2 & 7);
            xHi[sr2 * 8 + sw] = ph.v;  xLo[sr2 * 8 + sw] = pl.v;
            wHi[sr2 * 8 + sw] = qh.v;  wLo[sr2 * 8 + sw] = ql.v;
        }
        __syncthreads();
        int kwMax = (k0 == 768) ? 1 : 2;
        for (int kw = 0; kw < kwMax; ++kw) {
            bf16x8 ah[2], al[2], bh[2], bl[2];
#pragma unroll
            for (int i = 0; i < 2; ++i) {
                int m = mB2 + i * 16 + l15;
                int uu = (kw * 4 + l4) ^ (m & 7);
                ah[i] = BCAST(xHi[m * 8 + uu]);
                al[i] = BCAST(xLo[m * 8 + uu]);
                int n = nB2 + i * 16 + l15;
                int uv = (kw * 4 + l4) ^ (n & 7);
                bh[i] = BCAST(wHi[n * 8 + uv]);
                bl[i] = BCAST(wLo[n * 8 + uv]);
            }
#pragma unroll
            for (int i = 0; i < 2; ++i)
#pragma unroll
                for (int jj = 0; jj < 2; ++jj) {
                    accC[i][jj] = MFMA(ah[i], bh[jj], accC[i][jj]);
                    accC[i][jj] = MFMA(al[i], bh[jj], accC[i][jj]);
                    accC[i][jj] = MFMA(ah[i], bl[jj], accC[i][jj]);
                }
        }
        __syncthreads();
    }
#pragma unroll
    for (int mi = 0; mi < 2; ++mi)
#pragma unroll
        for (int ni = 0; ni < 2; ++ni)
#pragma unroll
            for (int q = 0; q < 4; ++q) {
                int row = bm2 + mB2 + mi * 16 + l4 * 4 + q;
                int col = bn2 + nB2 + ni * 16 + l15;
                c2[(size_t)row * 512 + col] = accC[mi][ni][q] + b2[col];
            }
}

// ================= persistent step loop =================
__global__ __launch_bounds__(256, 2) void k_loop(ushortT* __restrict__ hiA,
                                                 ushortT* __restrict__ hiB,
                                                 const ushortT* __restrict__ W1h,
                                                 const ushortT* __restrict__ W1l,
                                                 const ushortT* __restrict__ W1Th,
                                                 const ushortT* __restrict__ W1Tl,
                                                 const float* __restrict__ W0,
                                                 const float* __restrict__ b0,
                                                 const float* __restrict__ b1,
                                                 const float* __restrict__ c2,
                                                 float* __restrict__ outF,
                                                 unsigned* __restrict__ bar) {
    __shared__ u32x4 smem[3072];     // 48 KiB
    u32x4* AsR = smem;               // 1024: A tile [128][8], swizzled
    u32x4* BhS = smem + 1024;        //  512: W-hi tile [64][8]
    u32x4* BlS = smem + 1536;        //  512: W-lo tile [64][8]
    u32x4* aux = smem + 2048;        // 1024: doZ0 -> Bz0[16][64]; z1 -> Bs2[64][4] + As2[128][4]

    const int bid = blockIdx.x, t = threadIdx.x;
    const int lane = t & 63, w = t >> 6, l15 = lane & 15, l4 = lane >> 4;
    const int mB = w * 32;

    const int xcd = bid & 7, rblk = bid >> 3, bn_i = rblk & 7, grp = rblk >> 3;
    const int pidx = grp * 8 + xcd;
    const bool isZ1 = pidx < 32;
    const int bm = (pidx & 31) * 128, bn = bn_i * 64;
    const bool doZ0 = (!isZ1) && (bn_i == 0);

    // ---- one-time constant LDS staging ----
    if (isZ1) {
        if (t < 64) {   // Bs2[n][u]: B[n][k] = W0[k][bn+n], K window 32 (10 real)
#pragma unroll
            for (int u = 0; u < 4; ++u) {
                union { ushortT us[8]; u32x4 v; } pk;
#pragma unroll
                for (int e = 0; e < 8; ++e) {
                    int k = u * 8 + e;
                    pk.us[e] = (k < 10) ? f2b(W0[(size_t)k * 512 + bn + t]) : (ushortT)0;
                }
                aux[t * 4 + u] = pk.v;
            }
        }
    } else if (doZ0) {  // Bz0[c][64 units]: W0^T, 16 cols x K=512, swizzled
        int c = t >> 4, u0 = (t & 15) * 4;
#pragma unroll
        for (int j = 0; j < 4; ++j) {
            int U = u0 + j;
            union { ushortT us[8]; u32x4 v; } pk;
#pragma unroll
            for (int e = 0; e < 8; ++e)
                pk.us[e] = (c < 10) ? f2b(W0[(size_t)c * 512 + U * 8 + e]) : (ushortT)0;
            aux[c * 64 + ((U & ~7) | ((U & 7) ^ (c & 7)))] = pk.v;
        }
    }

    const int aOff = isZ1 ? OFF2B : OFF1B;   // src panel: z1 reads s2, z2 reads s1
    const int dOff = isZ1 ? OFF1B : OFF2B;   // dest layer
    const int oOff = isZ1 ? 10 : 522;
    const ushortT* __restrict__ Wbh = isZ1 ? W1h : W1Th;
    const ushortT* __restrict__ Wbl = isZ1 ? W1l : W1Tl;
    const int sr = t >> 1, sh = t & 1;       // A staging: 2 thr/row, 4 units each
    const int bnr = t >> 2, bju = t & 3;     // B staging: 4 thr/row, 2 units each

    // ---- persistent register state ----
    float b1r[4];
#pragma unroll
    for (int ni = 0; ni < 4; ++ni) b1r[ni] = isZ1 ? b1[bn + ni * 16 + l15] : 0.f;
    const float b0v = (doZ0 && l15 < 10) ? b0[l15] : 0.f;
    float c2r[2][4][4];
    if (!isZ1) {
#pragma unroll
        for (int mi = 0; mi < 2; ++mi)
#pragma unroll
            for (int ni = 0; ni < 4; ++ni)
#pragma unroll
                for (int q = 0; q < 4; ++q)
                    c2r[mi][ni][q] =
                        c2[(size_t)(bm + mB + mi * 16 + l4 * 4 + q) * 512 + bn + ni * 16 + l15];
    }
    float oldR[2][4][4];
#pragma unroll
    for (int mi = 0; mi < 2; ++mi)
#pragma unroll
        for (int ni = 0; ni < 4; ++ni)
#pragma unroll
            for (int q = 0; q < 4; ++q) oldR[mi][ni][q] = 0.f;
    float oldZ[2][4];
#pragma unroll
    for (int i = 0; i < 2; ++i)
#pragma unroll
        for (int q = 0; q < 4; ++q) oldZ[i][q] = 0.f;

    for (int ts = 0; ts < 30; ++ts) {
        const ushortT* __restrict__ sH = (ts & 1) ? hiB : hiA;
        ushortT* __restrict__ dH       = (ts & 1) ? hiA : hiB;
        const bool fin = (ts == 29);

        f32x4 acc[2][4], accZ[2];
#pragma unroll
        for (int mi = 0; mi < 2; ++mi)
#pragma unroll
            for (int ni = 0; ni < 4; ++ni) { f32x4 z = {0.f,0.f,0.f,0.f}; acc[mi][ni] = z; }
#pragma unroll
        for (int i = 0; i < 2; ++i) { f32x4 z = {0.f,0.f,0.f,0.f}; accZ[i] = z; }

        if (isZ1 && t < 128) {   // As2: s0 window for this step, zero-padded to K=32
            union { ushortT us[16]; u32x4 v2[2]; } pk;
#pragma unroll
            for (int e = 0; e < 16; ++e) pk.us[e] = 0;
            const ushortT* sp = sH + (size_t)(bm + t) * HSTR;
#pragma unroll
            for (int e = 0; e < 10; ++e) pk.us[e] = sp[e];
            u32x4 z = {0u, 0u, 0u, 0u};
            aux[256 + t * 4 + 0] = pk.v2[0];
            aux[256 + t * 4 + 1] = pk.v2[1];
            aux[256 + t * 4 + 2] = z;
            aux[256 + t * 4 + 3] = z;
        }

        // ---- software-pipelined K loop (reg-staged double buffer) ----
        u32x4 rA[2][4], rBh[2][2], rBl[2][2];
        {
            const u32x4* gA = (const u32x4*)(sH + (size_t)(bm + sr) * HSTR + aOff);
            const u32x4* gh = (const u32x4*)(Wbh + (size_t)(bn + bnr) * 512);
            const u32x4* gl = (const u32x4*)(Wbl + (size_t)(bn + bnr) * 512);
#pragma unroll
            for (int j = 0; j < 4; ++j) rA[0][j] = gA[sh * 4 + j];
#pragma unroll
            for (int j = 0; j < 2; ++j) { rBh[0][j] = gh[bju * 2 + j]; rBl[0][j] = gl[bju * 2 + j]; }
        }
#pragma unroll
        for (int it = 0; it < 8; ++it) {
            const int k0 = it * 64;
            const int cur = it & 1, nxt = cur ^ 1;
            __syncthreads();                      // prev compute done; LDS reusable
#pragma unroll
            for (int j = 0; j < 4; ++j) {
                int u = sh * 4 + j;
                AsR[sr * 8 + (u ^ (sr & 7))] = rA[cur][j];
            }
#pragma unroll
            for (int j = 0; j < 2; ++j) {
                int u = bju * 2 + j;
                BhS[bnr * 8 + (u ^ (bnr & 7))] = rBh[cur][j];
                BlS[bnr * 8 + (u ^ (bnr & 7))] = rBl[cur][j];
            }
            if (it < 7) {                         // prefetch next K tile into regs
                const int k1 = k0 + 64;
                const u32x4* gA = (const u32x4*)(sH + (size_t)(bm + sr) * HSTR + aOff + k1);
                const u32x4* gh = (const u32x4*)(Wbh + (size_t)(bn + bnr) * 512 + k1);
                const u32x4* gl = (const u32x4*)(Wbl + (size_t)(bn + bnr) * 512 + k1);
#pragma unroll
                for (int j = 0; j < 4; ++j) rA[nxt][j] = gA[sh * 4 + j];
#pragma unroll
                for (int j = 0; j < 2; ++j) { rBh[nxt][j] = gh[bju * 2 + j]; rBl[nxt][j] = gl[bju * 2 + j]; }
            }
            __syncthreads();                      // publish LDS
#pragma unroll
            for (int kw = 0; kw < 2; ++kw) {
                bf16x8 a[2], bh[4], bl[4];
#pragma unroll
                for (int mi = 0; mi < 2; ++mi) {
                    int m = mB + mi * 16 + l15;
                    a[mi] = BCAST(AsR[m * 8 + ((kw * 4 + l4) ^ (m & 7))]);
                }
#pragma unroll
                for (int ni = 0; ni < 4; ++ni) {
                    int n = ni * 16 + l15;
                    int u = (kw * 4 + l4) ^ (n & 7);
                    bh[ni] = BCAST(BhS[n * 8 + u]);
                    bl[ni] = BCAST(BlS[n * 8 + u]);
                }
#pragma unroll
                for (int mi = 0; mi < 2; ++mi)
#pragma unroll
                    for (int ni = 0; ni < 4; ++ni) {
                        acc[mi][ni] = MFMA(a[mi], bh[ni], acc[mi][ni]);
                        acc[mi][ni] = MFMA(a[mi], bl[ni], acc[mi][ni]);
                    }
                if (doZ0) {
                    int U = (k0 >> 3) + kw * 4 + l4;
                    bf16x8 bz = BCAST(aux[l15 * 64 + ((U & ~7) | ((U & 7) ^ (l15 & 7)))]);
                    accZ[0] = MFMA(a[0], bz, accZ[0]);
                    accZ[1] = MFMA(a[1], bz, accZ[1]);
                }
            }
        }
        if (isZ1) {   // s0 @ W0 extra K window
            bf16x8 a2[2], bb[4];
#pragma unroll
            for (int mi = 0; mi < 2; ++mi)
                a2[mi] = BCAST(aux[256 + (mB + mi * 16 + l15) * 4 + l4]);
#pragma unroll
            for (int ni = 0; ni < 4; ++ni)
                bb[ni] = BCAST(aux[(ni * 16 + l15) * 4 + l4]);
#pragma unroll
            for (int mi = 0; mi < 2; ++mi)
#pragma unroll
                for (int ni = 0; ni < 4; ++ni)
                    acc[mi][ni] = MFMA(a2[mi], bb[ni], acc[mi][ni]);
        }

        // ---- epilogue: v = clip(0.5*old(reg) + 0.5*(acc + bias)); old = v ----
        __syncthreads();   // all LDS reads done; AsR reusable as output staging
        ushortT* dlds = (ushortT*)AsR;
#pragma unroll
        for (int ni = 0; ni < 4; ++ni) {
            int gc = bn + ni * 16 + l15;
#pragma unroll
            for (int mi = 0; mi < 2; ++mi) {
#pragma unroll
                for (int q = 0; q < 4; ++q) {
                    float bias = isZ1 ? b1r[ni] : c2r[mi][ni][q];
                    float v = 0.5f * oldR[mi][ni][q] + 0.5f * (acc[mi][ni][q] + bias);
                    v = fminf(fmaxf(v, 0.f), 1.f);
                    oldR[mi][ni][q] = v;
                    if (fin) {
                        size_t gb = (size_t)bm + mB + mi * 16 + l4 * 4 + q;
                        outF[gb * CSTR + oOff + gc] = v;
                    } else {
                        dlds[(mB + mi * 16 + l4 * 4 + q) * 64 + ni * 16 + l15] = f2b(v);
                    }
                }
            }
        }
        if (doZ0 && l15 < 10) {
#pragma unroll
            for (int i = 0; i < 2; ++i) {
#pragma unroll
                for (int q = 0; q < 4; ++q) {
                    float v = 0.5f * oldZ[i][q] + 0.5f * (accZ[i][q] + b0v);
                    v = fminf(fmaxf(v, 0.f), 1.f);
                    oldZ[i][q] = v;
                    size_t gb = (size_t)bm + w * 32 + i * 16 + l4 * 4 + q;
                    if (fin) outF[gb * CSTR + l15] = v;
                    else     dH[gb * HSTR + l15] = f2b(v);
                }
            }
        }
        if (!fin) {
            __syncthreads();
            // coalesced 16B-per-lane tile store into this block's column slice
#pragma unroll
            for (int j = 0; j < 4; ++j) {
                int i = j * 256 + t;
                int row = i >> 3, u = i & 7;
                ((u32x4*)(dH + (size_t)(bm + row) * HSTR + dOff + bn))[u] = AsR[i];
            }
            grid_barrier(bar);
        }
    }
}

// ================= fallback per-step kernel (proven R6) =================
__global__ __launch_bounds__(256, 3) void k_step(const ushortT* __restrict__ sH,
                                                 ushortT* __restrict__ dH,
                                                 const ushortT* __restrict__ W1h,
                                                 const ushortT* __restrict__ W1l,
                                                 const ushortT* __restrict__ W1Th,
                                                 const ushortT* __restrict__ W1Tl,
                                                 const float* __restrict__ W0,
                                                 const float* __restrict__ b0,
                                                 const float* __restrict__ b1,
                                                 const float* __restrict__ c2,
                                                 float* __restrict__ outF) {
    __shared__ u32x4 smem[3072];
    u32x4* AsR = smem;
    u32x4* BhS = smem + 1024;
    u32x4* BlS = smem + 1536;
    u32x4* aux = smem + 2048;

    const int bid = blockIdx.x, t = threadIdx.x;
    const int lane = t & 63, w = t >> 6, l15 = lane & 15, l4 = lane >> 4;
    const int mB = w * 32;

    const int xcd = bid & 7, rblk = bid >> 3, bn_i = rblk & 7, grp = rblk >> 3;
    const int pidx = grp * 8 + xcd;
    const bool isZ1 = pidx < 32;
    const int bm = (pidx & 31) * 128, bn = bn_i * 64;
    const bool doZ0 = (!isZ1) && (bn_i == 0);

    if (isZ1) {
        if (t < 64) {
#pragma unroll
            for (int u = 0; u < 4; ++u) {
                union { ushortT us[8]; u32x4 v; } pk;
#pragma unroll
                for (int e = 0; e < 8; ++e) {
                    int k = u * 8 + e;
                    pk.us[e] = (k < 10) ? f2b(W0[(size_t)k * 512 + bn + t]) : (ushortT)0;
                }
                aux[t * 4 + u] = pk.v;
            }
        }
        if (t < 128) {
            union { ushortT us[16]; u32x4 v2[2]; } pk;
#pragma unroll
            for (int e = 0; e < 16; ++e) pk.us[e] = 0;
            const ushortT* sp = sH + (size_t)(bm + t) * HSTR;
#pragma unroll
            for (int e = 0; e < 10; ++e) pk.us[e] = sp[e];
            u32x4 z = {0u, 0u, 0u, 0u};
            aux[256 + t * 4 + 0] = pk.v2[0];
            aux[256 + t * 4 + 1] = pk.v2[1];
            aux[256 + t * 4 + 2] = z;
            aux[256 + t * 4 + 3] = z;
        }
    } else if (doZ0) {
        int c = t >> 4, u0 = (t & 15) * 4;
#pragma unroll
        for (int j = 0; j < 4; ++j) {
            int U = u0 + j;
            union { ushortT us[8]; u32x4 v; } pk;
#pragma unroll
            for (int e = 0; e < 8; ++e)
                pk.us[e] = (c < 10) ? f2b(W0[(size_t)c * 512 + U * 8 + e]) : (ushortT)0;
            aux[c * 64 + ((U & ~7) | ((U & 7) ^ (c & 7)))] = pk.v;
        }
    }

    const int aOff = isZ1 ? OFF2B : OFF1B;
    const int dOff = isZ1 ? OFF1B : OFF2B;
    const int oOff = isZ1 ? 10 : 522;
    const ushortT* __restrict__ Wbh = isZ1 ? W1h : W1Th;
    const ushortT* __restrict__ Wbl = isZ1 ? W1l : W1Tl;
    const int sr = t >> 1, sh = t & 1;
    const int bnr = t >> 2, bju = t & 3;
    const bool fin = (outF != nullptr);

    f32x4 acc[2][4], accZ[2];
#pragma unroll
    for (int mi = 0; mi < 2; ++mi)
#pragma unroll
        for (int ni = 0; ni < 4; ++ni) { f32x4 z = {0.f,0.f,0.f,0.f}; acc[mi][ni] = z; }
#pragma unroll
    for (int i = 0; i < 2; ++i) { f32x4 z = {0.f,0.f,0.f,0.f}; accZ[i] = z; }

    u32x4 rA[2][4], rBh[2][2], rBl[2][2];
    {
        const u32x4* gA = (const u32x4*)(sH + (size_t)(bm + sr) * HSTR + aOff);
        const u32x4* gh = (const u32x4*)(Wbh + (size_t)(bn + bnr) * 512);
        const u32x4* gl = (const u32x4*)(Wbl + (size_t)(bn + bnr) * 512);
#pragma unroll
        for (int j = 0; j < 4; ++j) rA[0][j] = gA[sh * 4 + j];
#pragma unroll
        for (int j = 0; j < 2; ++j) { rBh[0][j] = gh[bju * 2 + j]; rBl[0][j] = gl[bju * 2 + j]; }
    }
#pragma unroll
    for (int it = 0; it < 8; ++it) {
        const int k0 = it * 64;
        const int cur = it & 1, nxt = cur ^ 1;
        __syncthreads();
#pragma unroll
        for (int j = 0; j < 4; ++j) {
            int u = sh * 4 + j;
            AsR[sr * 8 + (u ^ (sr & 7))] = rA[cur][j];
        }
#pragma unroll
        for (int j = 0; j < 2; ++j) {
            int u = bju * 2 + j;
            BhS[bnr * 8 + (u ^ (bnr & 7))] = rBh[cur][j];
            BlS[bnr * 8 + (u ^ (bnr & 7))] = rBl[cur][j];
        }
        if (it < 7) {
            const int k1 = k0 + 64;
            const u32x4* gA = (const u32x4*)(sH + (size_t)(bm + sr) * HSTR + aOff + k1);
            const u32x4* gh = (const u32x4*)(Wbh + (size_t)(bn + bnr) * 512 + k1);
            const u32x4* gl = (const u32x4*)(Wbl + (size_t)(bn + bnr) * 512 + k1);
#pragma unroll
            for (int j = 0; j < 4; ++j) rA[nxt][j] = gA[sh * 4 + j];
#pragma unroll
            for (int j = 0; j < 2; ++j) { rBh[nxt][j] = gh[bju * 2 + j]; rBl[nxt][j] = gl[bju * 2 + j]; }
        }
        __syncthreads();
#pragma unroll
        for (int kw = 0; kw < 2; ++kw) {
            bf16x8 a[2], bh[4], bl[4];
#pragma unroll
            for (int mi = 0; mi < 2; ++mi) {
                int m = mB + mi * 16 + l15;
                a[mi] = BCAST(AsR[m * 8 + ((kw * 4 + l4) ^ (m & 7))]);
            }
#pragma unroll
            for (int ni = 0; ni < 4; ++ni) {
                int n = ni * 16 + l15;
                int u = (kw * 4 + l4) ^ (n & 7);
                bh[ni] = BCAST(BhS[n * 8 + u]);
                bl[ni] = BCAST(BlS[n * 8 + u]);
            }
#pragma unroll
            for (int mi = 0; mi < 2; ++mi)
#pragma unroll
                for (int ni = 0; ni < 4; ++ni) {
                    acc[mi][ni] = MFMA(a[mi], bh[ni], acc[mi][ni]);
                    acc[mi][ni] = MFMA(a[mi], bl[ni], acc[mi][ni]);
                }
            if (doZ0) {
                int U = (k0 >> 3) + kw * 4 + l4;
                bf16x8 bz = BCAST(aux[l15 * 64 + ((U & ~7) | ((U & 7) ^ (l15 & 7)))]);
                accZ[0] = MFMA(a[0], bz, accZ[0]);
                accZ[1] = MFMA(a[1], bz, accZ[1]);
            }
        }
    }
    if (isZ1) {
        bf16x8 a2[2], bb[4];
#pragma unroll
        for (int mi = 0; mi < 2; ++mi)
            a2[mi] = BCAST(aux[256 + (mB + mi * 16 + l15) * 4 + l4]);
#pragma unroll
        for (int ni = 0; ni < 4; ++ni)
            bb[ni] = BCAST(aux[(ni * 16 + l15) * 4 + l4]);
#pragma unroll
        for (int mi = 0; mi < 2; ++mi)
#pragma unroll
            for (int ni = 0; ni < 4; ++ni)
                acc[mi][ni] = MFMA(a2[mi], bb[ni], acc[mi][ni]);
    }

    __syncthreads();
    if (fin) {
#pragma unroll
        for (int ni = 0; ni < 4; ++ni) {
            int gc = bn + ni * 16 + l15;
            float biasN = isZ1 ? b1[gc] : 0.f;
#pragma unroll
            for (int mi = 0; mi < 2; ++mi) {
#pragma unroll
                for (int q = 0; q < 4; ++q) {
                    size_t gb = (size_t)bm + mB + mi * 16 + l4 * 4 + q;
                    float bias = isZ1 ? biasN : c2[gb * 512 + gc];
                    float old = b2f(sH[gb * HSTR + dOff + gc]);
                    float v = 0.5f * old + 0.5f * (acc[mi][ni][q] + bias);
                    v = fminf(fmaxf(v, 0.f), 1.f);
                    outF[gb * CSTR + oOff + gc] = v;
                }
            }
        }
        if (doZ0 && l15 < 10) {
            float b0vv = b0[l15];
#pragma unroll
            for (int i = 0; i < 2; ++i) {
#pragma unroll
                for (int q = 0; q < 4; ++q) {
                    size_t gb = (size_t)bm + w * 32 + i * 16 + l4 * 4 + q;
                    float old = b2f(sH[gb * HSTR + l15]);
                    float v = 0.5f * old + 0.5f * (accZ[i][q] + b0vv);
                    v = fminf(fmaxf(v, 0.f), 1.f);
                    outF[gb * CSTR + l15] = v;
                }
            }
        }
    } else {
        ushortT* dlds = (ushortT*)AsR;
#pragma unroll
        for (int ni = 0; ni < 4; ++ni) {
            int gc = bn + ni * 16 + l15;
            float biasN = isZ1 ? b1[gc] : 0.f;
#pragma unroll
            for (int mi = 0; mi < 2; ++mi) {
#pragma unroll
                for (int q = 0; q < 4; ++q) {
                    size_t gb = (size_t)bm + mB + mi * 16 + l4 * 4 + q;
                    float bias = isZ1 ? biasN : c2[gb * 512 + gc];
                    float old = b2f(sH[gb * HSTR + dOff + gc]);
                    float v = 0.5f * old + 0.5f * (acc[mi][ni][q] + bias);
                    v = fminf(fmaxf(v, 0.f), 1.f);
                    dlds[(mB + mi * 16 + l4 * 4 + q) * 64 + ni * 16 + l15] = f2b(v);
                }
            }
        }
        if (doZ0 && l15 < 10) {
            float b0vv = b0[l15];
#pragma unroll
            for (int i = 0; i < 2; ++i) {
#pragma unroll
                for (int q = 0; q < 4; ++q) {
                    size_t gb = (size_t)bm + w * 32 + i * 16 + l4 * 4 + q;
                    float old = b2f(sH[gb * HSTR + l15]);
                    float v = 0.5f * old + 0.5f * (accZ[i][q] + b0vv);
                    v = fminf(fmaxf(v, 0.f), 1.f);
                    dH[gb * HSTR + l15] = f2b(v);
                }
            }
        }
        __syncthreads();
#pragma unroll
        for (int j = 0; j < 4; ++j) {
            int i = j * 256 + t;
            int row = i >> 3, u = i & 7;
            ((u32x4*)(dH + (size_t)(bm + row) * HSTR + dOff + bn))[u] = AsR[i];
        }
    }
}

extern "C" void kernel_launch(void* const* d_in, const int* in_sizes, int n_in,
                              void* d_out, int out_size, void* d_ws, size_t ws_size,
                              hipStream_t stream) {
    const float* x  = (const float*)d_in[3];
    const float* W0 = (const float*)d_in[4];
    const float* b0 = (const float*)d_in[5];
    const float* W1 = (const float*)d_in[6];
    const float* b1 = (const float*)d_in[7];
    const float* W2 = (const float*)d_in[8];
    const float* b2 = (const float*)d_in[9];

    // buffer A in d_out: 4096*1056*2 = 8,650,752 B <= 16,943,104 B
    ushortT* hiA = (ushortT*)d_out;
    // ws: hiB | c2 f32 | W1h | W1l | W1Th | W1Tl | bar  (~19.1 MB)
    ushortT* hiB = (ushortT*)d_ws;
    float*   c2  = (float*)(hiB + (size_t)4096 * HSTR);
    ushortT* W1h = (ushortT*)(c2 + (size_t)4096 * 512);
    ushortT* W1l  = W1h + 512 * 512;
    ushortT* W1Th = W1l + 512 * 512;
    ushortT* W1Tl = W1Th + 512 * 512;
    unsigned* bar = (unsigned*)(W1Tl + 512 * 512);

    const int zeroN = (int)((size_t)4096 * HSTR * sizeof(ushortT) / sizeof(u32x4));
    k_zero<<<1024, 256, 0, stream>>>((u32x4*)hiA, zeroN, bar);
    k_prep<<<64, 256, 0, stream>>>(W1, W1h, W1l, W1Th, W1Tl);
    k_c2<<<512, 256, 0, stream>>>(x, W2, b2, c2);

    // residency guard for the persistent kernel: need >= 2 blocks/CU (512 total)
    int nb = 0;
    hipError_t qe = hipOccupancyMaxActiveBlocksPerMultiprocessor(&nb, k_loop, 256, 0);
    if (qe == hipSuccess && nb >= 2) {
        k_loop<<<NBLK, 256, 0, stream>>>(hiA, hiB, W1h, W1l, W1Th, W1Tl,
                                         W0, b0, b1, c2, (float*)d_out, bar);
    } else {
        for (int ts = 0; ts < 30; ++ts) {
            const ushortT* sH = (ts & 1) ? hiB : hiA;
            ushortT* dH       = (ts & 1) ? hiA : hiB;
            float* outF = (ts == 29) ? (float*)d_out : nullptr;
            k_step<<<NBLK, 256, 0, stream>>>(sH, dH, W1h, W1l, W1Th, W1Tl,
                                             W0, b0, b1, c2, outF);
        }
    }
}

// Round 8
// 811.436 us; speedup vs baseline: 3.8505x; 1.0006x over previous
//
#include <hip/hip_runtime.h>

typedef unsigned short ushortT;
typedef short bf16x8 __attribute__((ext_vector_type(8)));
typedef float f32x4 __attribute__((ext_vector_type(4)));
typedef unsigned int u32x4 __attribute__((ext_vector_type(4)));

// EqProp free phase, B=4096, layers [10,512,512 | x=784 clamped], T=30, DT=0.5.
// States stay in [0,1] => rho(s)=s, rhop(s)=1.
// State: SINGLE bf16 plane, row stride 1056: [0,10)=s0, [32,544)=s1, [544,1056)=s2.
// Weights W1 split hi/lo bf16 (fp24-accurate), resident in LDS (immune to the
// grid barrier's L2 writeback/invalidate). Persistent kernel k_loop2:
// 256 blocks x 512 thr, 1 block/CU @ 160KB LDS; block owns 256 rows x 64 cols
// of one role. c2 tile + previous output + biases in registers across steps.
// Fallback: 30 per-step launches (proven R6 k_step) if attribute/occupancy fails.
#define HSTR 1056
#define OFF1B 32
#define OFF2B 544
#define CSTR 1034
#define NBLK2 256

__device__ __forceinline__ ushortT f2b(float f) {
    union { float f; unsigned u; } v; v.f = f;
    return (ushortT)((v.u + 0x7FFFu + ((v.u >> 16) & 1u)) >> 16);  // RNE
}
__device__ __forceinline__ float b2f(ushortT b) {
    union { unsigned u; float f; } v; v.u = ((unsigned)b) << 16;
    return v.f;
}
__device__ __forceinline__ void split2(float f, ushortT& h, ushortT& l) {
    h = f2b(f);
    l = f2b(f - b2f(h));
}

#define MFMA(a, b, c) __builtin_amdgcn_mfma_f32_16x16x32_bf16(a, b, c, 0, 0, 0)
#define BCAST(x) __builtin_bit_cast(bf16x8, x)

// sense-reversing grid barrier; fences come from the atomic orderings themselves
// (release: wbl2 before inc; acquire: inv after observing generation).
__device__ __forceinline__ void grid_barrier(unsigned* bar) {
    __syncthreads();
    if (threadIdx.x == 0) {
        unsigned g = __hip_atomic_load(bar + 1, __ATOMIC_RELAXED, __HIP_MEMORY_SCOPE_AGENT);
        unsigned a = __hip_atomic_fetch_add(bar, 1u, __ATOMIC_ACQ_REL, __HIP_MEMORY_SCOPE_AGENT);
        if (a == NBLK2 - 1u) {
            __hip_atomic_store(bar, 0u, __ATOMIC_RELAXED, __HIP_MEMORY_SCOPE_AGENT);
            __hip_atomic_fetch_add(bar + 1, 1u, __ATOMIC_ACQ_REL, __HIP_MEMORY_SCOPE_AGENT);
        } else {
            while (__hip_atomic_load(bar + 1, __ATOMIC_RELAXED, __HIP_MEMORY_SCOPE_AGENT) == g)
                __builtin_amdgcn_s_sleep(8);
            (void)__hip_atomic_load(bar + 1, __ATOMIC_ACQUIRE, __HIP_MEMORY_SCOPE_AGENT);
        }
    }
    __syncthreads();
}

// ---------------- zero state buffer A + barrier words ----------------
__global__ void k_zero(u32x4* __restrict__ p, int n, unsigned* __restrict__ bar) {
    u32x4 z = {0u, 0u, 0u, 0u};
    for (int i = blockIdx.x * blockDim.x + threadIdx.x; i < n; i += gridDim.x * blockDim.x)
        p[i] = z;
    if (blockIdx.x == 0 && threadIdx.x == 0) { bar[0] = 0u; bar[1] = 0u; }
}

// ---------------- W1 -> split bf16 hi/lo, row-major + transpose ----------------
__global__ __launch_bounds__(256) void k_prep(const float* __restrict__ W1,
                                              ushortT* __restrict__ W1h,
                                              ushortT* __restrict__ W1l,
                                              ushortT* __restrict__ W1Th,
                                              ushortT* __restrict__ W1Tl) {
    __shared__ float tile[64][65];
    const int ti = blockIdx.x >> 3, tj = blockIdx.x & 7;
    const int t = threadIdx.x;
#pragma unroll
    for (int q = 0; q < 16; ++q) {
        int rr = q * 4 + (t >> 6), cc = t & 63;
        float v = W1[(size_t)(ti * 64 + rr) * 512 + tj * 64 + cc];
        tile[rr][cc] = v;
        ushortT h, l; split2(v, h, l);
        W1h[(size_t)(ti * 64 + rr) * 512 + tj * 64 + cc] = h;
        W1l[(size_t)(ti * 64 + rr) * 512 + tj * 64 + cc] = l;
    }
    __syncthreads();
#pragma unroll
    for (int q = 0; q < 16; ++q) {
        int rr = q * 4 + (t >> 6), cc = t & 63;
        ushortT h, l; split2(tile[cc][rr], h, l);
        W1Th[(size_t)(tj * 64 + rr) * 512 + ti * 64 + cc] = h;
        W1Tl[(size_t)(tj * 64 + rr) * 512 + ti * 64 + cc] = l;
    }
}

// ---------------- c2 = rho(x) @ W2^T + b2 via split-bf16 MFMA (3-pass) ----------------
__global__ __launch_bounds__(256) void k_c2(const float* __restrict__ x,
                                            const float* __restrict__ W2,
                                            const float* __restrict__ b2,
                                            float* __restrict__ c2) {
    __shared__ u32x4 cs[2048];
    u32x4* xHi = cs;
    u32x4* xLo = cs + 512;
    u32x4* wHi = cs + 1024;
    u32x4* wLo = cs + 1536;
    const int bid = blockIdx.x, t = threadIdx.x;
    const int lane = t & 63, w = t >> 6, l15 = lane & 15, l4 = lane >> 4;
    const int bm2 = (bid >> 3) * 64, bn2 = (bid & 7) * 64;
    const int mB2 = (w >> 1) * 32, nB2 = (w & 1) * 32;
    const int sr2 = t >> 2, ub = (t & 3) * 2;
    f32x4 accC[2][2];
#pragma unroll
    for (int i = 0; i < 2; ++i)
#pragma unroll
        for (int j = 0; j < 2; ++j) { f32x4 z = {0.f, 0.f, 0.f, 0.f}; accC[i][j] = z; }
    for (int k0 = 0; k0 < 784; k0 += 64) {
#pragma unroll
        for (int j = 0; j < 2; ++j) {
            int u = ub + j;
            bool valid = (k0 + u * 8 + 8 <= 784);
            union { ushortT us[8]; u32x4 v; } ph, pl, qh, ql;
            if (valid) {
                const float* srcx = x  + (size_t)(bm2 + sr2) * 784 + k0 + u * 8;
                const float* srcw = W2 + (size_t)(bn2 + sr2) * 784 + k0 + u * 8;
#pragma unroll
                for (int e = 0; e < 8; ++e) {
                    float cx = fminf(fmaxf(srcx[e], 0.f), 1.f);
                    split2(cx, ph.us[e], pl.us[e]);
                    split2(srcw[e], qh.us[e], ql.us[e]);
                }
            } else {
#pragma unroll
                for (int e = 0; e < 8; ++e) { ph.us[e]=0; pl.us[e]=0; qh.us[e]=0; ql.us[e]=0; }
            }
            int sw = u ^ (sr2 & 7);
            xHi[sr2 * 8 + sw] = ph.v;  xLo[sr2 * 8 + sw] = pl.v;
            wHi[sr2 * 8 + sw] = qh.v;  wLo[sr2 * 8 + sw] = ql.v;
        }
        __syncthreads();
        int kwMax = (k0 == 768) ? 1 : 2;
        for (int kw = 0; kw < kwMax; ++kw) {
            bf16x8 ah[2], al[2], bh[2], bl[2];
#pragma unroll
            for (int i = 0; i < 2; ++i) {
                int m = mB2 + i * 16 + l15;
                int uu = (kw * 4 + l4) ^ (m & 7);
                ah[i] = BCAST(xHi[m * 8 + uu]);
                al[i] = BCAST(xLo[m * 8 + uu]);
                int n = nB2 + i * 16 + l15;
                int uv = (kw * 4 + l4) ^ (n & 7);
                bh[i] = BCAST(wHi[n * 8 + uv]);
                bl[i] = BCAST(wLo[n * 8 + uv]);
            }
#pragma unroll
            for (int i = 0; i < 2; ++i)
#pragma unroll
                for (int jj = 0; jj < 2; ++jj) {
                    accC[i][jj] = MFMA(ah[i], bh[jj], accC[i][jj]);
                    accC[i][jj] = MFMA(al[i], bh[jj], accC[i][jj]);
                    accC[i][jj] = MFMA(ah[i], bl[jj], accC[i][jj]);
                }
        }
        __syncthreads();
    }
#pragma unroll
    for (int mi = 0; mi < 2; ++mi)
#pragma unroll
        for (int ni = 0; ni < 2; ++ni)
#pragma unroll
            for (int q = 0; q < 4; ++q) {
                int row = bm2 + mB2 + mi * 16 + l4 * 4 + q;
                int col = bn2 + nB2 + ni * 16 + l15;
                c2[(size_t)row * 512 + col] = accC[mi][ni][q] + b2[col];
            }
}

// ================= persistent loop, weights in LDS =================
// 256 blocks x 512 threads, 1 block/CU @ 160 KB LDS.
// Block: role (z1|z2), panel-pair P (256 rows), col-slice cb (64 cols).
// xcd = bid&7; all blocks touching panel P (both roles, all 8 col-slices)
// share xcd = P&7 (L2 locality heuristic only; fences guarantee correctness).
__global__ __launch_bounds__(512, 2) void k_loop2(ushortT* __restrict__ hiA,
                                                  ushortT* __restrict__ hiB,
                                                  const ushortT* __restrict__ W1h,
                                                  const ushortT* __restrict__ W1l,
                                                  const ushortT* __restrict__ W1Th,
                                                  const ushortT* __restrict__ W1Tl,
                                                  const float* __restrict__ W0,
                                                  const float* __restrict__ b0,
                                                  const float* __restrict__ b1,
                                                  const float* __restrict__ c2,
                                                  float* __restrict__ outF,
                                                  unsigned* __restrict__ bar) {
    extern __shared__ u32x4 smem[];      // 10240 units = 160 KB
    u32x4* WhS = smem;                   // 4096: W-hi [64 n][64 u], swizzled
    u32x4* WlS = smem + 4096;            // 4096: W-lo
    u32x4* AsR = smem + 8192;            // 1024: A tile [256 r][4 u] / As2 / out staging
    u32x4* aux = smem + 9216;            // 1024: z1 -> Bs2 [64][4]; doZ0 -> Bz0 [16][64]

    const int bid = blockIdx.x, t = threadIdx.x;
    const int lane = t & 63, w = t >> 6, l15 = lane & 15, l4 = lane >> 4;
    const int mB = w * 32;               // wave rows [mB, mB+32)

    const int xcd = bid & 7, rblk = bid >> 3;
    const int cb = rblk & 7, rp = rblk >> 3;
    const int P = ((rp & 1) << 3) | xcd;         // panel-pair [0,16)
    const bool isZ1 = (rp >> 1) == 0;
    const int bm = P * 256, bn = cb * 64;
    const bool doZ0 = (!isZ1) && (cb == 0);

    const int aOff = isZ1 ? OFF2B : OFF1B;       // z1 reads s2, z2 reads s1
    const int dOff = isZ1 ? OFF1B : OFF2B;
    const int oOff = isZ1 ? 10 : 522;
    const ushortT* __restrict__ Wbh = isZ1 ? W1h : W1Th;
    const ushortT* __restrict__ Wbl = isZ1 ? W1l : W1Tl;

    // ---- one-time: weight slice -> LDS (swizzled), 128 KB ----
    {
        const int wn = t >> 3;           // 64 rows, 8 thr/row
        const int wu0 = (t & 7) * 8;     // 8 units each
        const u32x4* gh = (const u32x4*)(Wbh + (size_t)(bn + wn) * 512);
        const u32x4* gl = (const u32x4*)(Wbl + (size_t)(bn + wn) * 512);
#pragma unroll
        for (int j = 0; j < 8; ++j) {
            int U = wu0 + j;
            int sU = U ^ (wn & 7);
            WhS[wn * 64 + sU] = gh[U];
            WlS[wn * 64 + sU] = gl[U];
        }
    }
    // ---- one-time aux ----
    if (isZ1) {
        if (t < 256) {   // Bs2[n][u]: B[n][k] = W0[k][bn+n], K=32 (10 real)
            int n = t >> 2, u = t & 3;
            union { ushortT us[8]; u32x4 v; } pk;
#pragma unroll
            for (int e = 0; e < 8; ++e) {
                int k = u * 8 + e;
                pk.us[e] = (k < 10) ? f2b(W0[(size_t)k * 512 + bn + n]) : (ushortT)0;
            }
            aux[n * 4 + u] = pk.v;
        }
    } else if (doZ0) {   // Bz0[c][u]: B[c][k] = W0[c][k], 16 x 512, swizzled
        int c = t >> 5, u0 = (t & 31) * 2;
#pragma unroll
        for (int j = 0; j < 2; ++j) {
            int U = u0 + j;
            union { ushortT us[8]; u32x4 v; } pk;
#pragma unroll
            for (int e = 0; e < 8; ++e)
                pk.us[e] = (c < 10) ? f2b(W0[(size_t)c * 512 + U * 8 + e]) : (ushortT)0;
            aux[c * 64 + (U ^ (c & 7))] = pk.v;
        }
    }

    // ---- persistent registers ----
    float b1r[4];
#pragma unroll
    for (int ni = 0; ni < 4; ++ni) b1r[ni] = isZ1 ? b1[bn + ni * 16 + l15] : 0.f;
    const float b0v = (doZ0 && l15 < 10) ? b0[l15] : 0.f;
    float c2r[2][4][4];
    if (!isZ1) {
#pragma unroll
        for (int mi = 0; mi < 2; ++mi)
#pragma unroll
            for (int ni = 0; ni < 4; ++ni)
#pragma unroll
                for (int q = 0; q < 4; ++q)
                    c2r[mi][ni][q] =
                        c2[(size_t)(bm + mB + mi * 16 + l4 * 4 + q) * 512 + bn + ni * 16 + l15];
    }
    float oldR[2][4][4];
#pragma unroll
    for (int mi = 0; mi < 2; ++mi)
#pragma unroll
        for (int ni = 0; ni < 4; ++ni)
#pragma unroll
            for (int q = 0; q < 4; ++q) oldR[mi][ni][q] = 0.f;
    float oldZ[2][4];
#pragma unroll
    for (int i = 0; i < 2; ++i)
#pragma unroll
        for (int q = 0; q < 4; ++q) oldZ[i][q] = 0.f;

    const int sr = t >> 1, su = (t & 1) * 2;     // A staging: 2 thr/row, 2 units each

    for (int ts = 0; ts < 30; ++ts) {
        const ushortT* __restrict__ sH = (ts & 1) ? hiB : hiA;
        ushortT* __restrict__ dH       = (ts & 1) ? hiA : hiB;
        const bool fin = (ts == 29);

        f32x4 acc[2][4], accZ[2];
#pragma unroll
        for (int mi = 0; mi < 2; ++mi)
#pragma unroll
            for (int ni = 0; ni < 4; ++ni) { f32x4 z = {0.f,0.f,0.f,0.f}; acc[mi][ni] = z; }
#pragma unroll
        for (int i = 0; i < 2; ++i) { f32x4 z = {0.f,0.f,0.f,0.f}; accZ[i] = z; }

        // ---- K loop: 16 iters x K=32, reg-prefetch into single LDS A-tile ----
        u32x4 rA[2][2];
        {
            const u32x4* gA = (const u32x4*)(sH + (size_t)(bm + sr) * HSTR + aOff);
            rA[0][0] = gA[su];  rA[0][1] = gA[su + 1];
        }
#pragma unroll
        for (int it = 0; it < 16; ++it) {
            const int cur = it & 1, nxt = cur ^ 1;
            __syncthreads();                      // prev compute done; AsR reusable
            AsR[sr * 4 + ( su      ^ (sr & 3))] = rA[cur][0];
            AsR[sr * 4 + ((su + 1) ^ (sr & 3))] = rA[cur][1];
            if (it < 15) {
                const u32x4* gA = (const u32x4*)(sH + (size_t)(bm + sr) * HSTR + aOff + (it + 1) * 32);
                rA[nxt][0] = gA[su];  rA[nxt][1] = gA[su + 1];
            }
            __syncthreads();                      // publish
            bf16x8 a[2], bh[4], bl[4];
#pragma unroll
            for (int mi = 0; mi < 2; ++mi) {
                int m = mB + mi * 16 + l15;
                a[mi] = BCAST(AsR[m * 4 + (l4 ^ (m & 3))]);
            }
            const int U = it * 4 + l4;
#pragma unroll
            for (int ni = 0; ni < 4; ++ni) {
                int n = ni * 16 + l15;
                int sU = U ^ (n & 7);
                bh[ni] = BCAST(WhS[n * 64 + sU]);
                bl[ni] = BCAST(WlS[n * 64 + sU]);
            }
#pragma unroll
            for (int mi = 0; mi < 2; ++mi)
#pragma unroll
                for (int ni = 0; ni < 4; ++ni) {
                    acc[mi][ni] = MFMA(a[mi], bh[ni], acc[mi][ni]);
                    acc[mi][ni] = MFMA(a[mi], bl[ni], acc[mi][ni]);
                }
            if (doZ0) {
                bf16x8 bz = BCAST(aux[l15 * 64 + (U ^ (l15 & 7))]);
                accZ[0] = MFMA(a[0], bz, accZ[0]);
                accZ[1] = MFMA(a[1], bz, accZ[1]);
            }
        }
        __syncthreads();                          // compute done; AsR free
        if (isZ1) {   // s0 @ W0 extra K window (As2 overlays AsR)
            if (t < 256) {
                union { ushortT us[16]; u32x4 v2[2]; } pk;
#pragma unroll
                for (int e = 0; e < 16; ++e) pk.us[e] = 0;
                const ushortT* sp = sH + (size_t)(bm + t) * HSTR;
#pragma unroll
                for (int e = 0; e < 10; ++e) pk.us[e] = sp[e];
                u32x4 z = {0u, 0u, 0u, 0u};
                AsR[t * 4 + 0] = pk.v2[0];
                AsR[t * 4 + 1] = pk.v2[1];
                AsR[t * 4 + 2] = z;
                AsR[t * 4 + 3] = z;
            }
            __syncthreads();
            bf16x8 a2[2], bb[4];
#pragma unroll
            for (int mi = 0; mi < 2; ++mi)
                a2[mi] = BCAST(AsR[(mB + mi * 16 + l15) * 4 + l4]);
#pragma unroll
            for (int ni = 0; ni < 4; ++ni)
                bb[ni] = BCAST(aux[(ni * 16 + l15) * 4 + l4]);
#pragma unroll
            for (int mi = 0; mi < 2; ++mi)
#pragma unroll
                for (int ni = 0; ni < 4; ++ni)
                    acc[mi][ni] = MFMA(a2[mi], bb[ni], acc[mi][ni]);
        }

        // ---- epilogue: v = clip(0.5*old(reg) + 0.5*(acc + bias)) ----
        if (fin) {
#pragma unroll
            for (int ni = 0; ni < 4; ++ni) {
                int gc = bn + ni * 16 + l15;
#pragma unroll
                for (int mi = 0; mi < 2; ++mi) {
#pragma unroll
                    for (int q = 0; q < 4; ++q) {
                        float bias = isZ1 ? b1r[ni] : c2r[mi][ni][q];
                        float v = 0.5f * oldR[mi][ni][q] + 0.5f * (acc[mi][ni][q] + bias);
                        v = fminf(fmaxf(v, 0.f), 1.f);
                        size_t gb = (size_t)bm + mB + mi * 16 + l4 * 4 + q;
                        outF[gb * CSTR + oOff + gc] = v;
                    }
                }
            }
            if (doZ0 && l15 < 10) {
#pragma unroll
                for (int i = 0; i < 2; ++i) {
#pragma unroll
                    for (int q = 0; q < 4; ++q) {
                        float v = 0.5f * oldZ[i][q] + 0.5f * (accZ[i][q] + b0v);
                        v = fminf(fmaxf(v, 0.f), 1.f);
                        size_t gb = (size_t)bm + mB + i * 16 + l4 * 4 + q;
                        outF[gb * CSTR + l15] = v;
                    }
                }
            }
        } else {
            if (doZ0 && l15 < 10) {
#pragma unroll
                for (int i = 0; i < 2; ++i) {
#pragma unroll
                    for (int q = 0; q < 4; ++q) {
                        float v = 0.5f * oldZ[i][q] + 0.5f * (accZ[i][q] + b0v);
                        v = fminf(fmaxf(v, 0.f), 1.f);
                        oldZ[i][q] = v;
                        size_t gb = (size_t)bm + mB + i * 16 + l4 * 4 + q;
                        dH[gb * HSTR + l15] = f2b(v);
                    }
                }
            }
            // two row-phases of 128: stage bf16 tile in AsR, store coalesced
#pragma unroll
            for (int h = 0; h < 2; ++h) {
                __syncthreads();                  // prior AsR reads / stores done
                if ((w >> 2) == h) {
                    ushortT* dlds = (ushortT*)AsR;
#pragma unroll
                    for (int ni = 0; ni < 4; ++ni) {
#pragma unroll
                        for (int mi = 0; mi < 2; ++mi) {
#pragma unroll
                            for (int q = 0; q < 4; ++q) {
                                float bias = isZ1 ? b1r[ni] : c2r[mi][ni][q];
                                float v = 0.5f * oldR[mi][ni][q] + 0.5f * (acc[mi][ni][q] + bias);
                                v = fminf(fmaxf(v, 0.f), 1.f);
                                oldR[mi][ni][q] = v;
                                int lrow = mB - h * 128 + mi * 16 + l4 * 4 + q;
                                dlds[lrow * 64 + ni * 16 + l15] = f2b(v);
                            }
                        }
                    }
                }
                __syncthreads();
#pragma unroll
                for (int j = 0; j < 2; ++j) {
                    int i = t + j * 512;
                    int row = i >> 3, u = i & 7;
                    ((u32x4*)(dH + (size_t)(bm + h * 128 + row) * HSTR + dOff + bn))[u] = AsR[i];
                }
            }
            grid_barrier(bar);
        }
    }
}

// ================= fallback per-step kernel (proven R6) =================
__global__ __launch_bounds__(256, 3) void k_step(const ushortT* __restrict__ sH,
                                                 ushortT* __restrict__ dH,
                                                 const ushortT* __restrict__ W1h,
                                                 const ushortT* __restrict__ W1l,
                                                 const ushortT* __restrict__ W1Th,
                                                 const ushortT* __restrict__ W1Tl,
                                                 const float* __restrict__ W0,
                                                 const float* __restrict__ b0,
                                                 const float* __restrict__ b1,
                                                 const float* __restrict__ c2,
                                                 float* __restrict__ outF) {
    __shared__ u32x4 smem[3072];
    u32x4* AsR = smem;
    u32x4* BhS = smem + 1024;
    u32x4* BlS = smem + 1536;
    u32x4* aux = smem + 2048;

    const int bid = blockIdx.x, t = threadIdx.x;
    const int lane = t & 63, w = t >> 6, l15 = lane & 15, l4 = lane >> 4;
    const int mB = w * 32;

    const int xcd = bid & 7, rblk = bid >> 3, bn_i = rblk & 7, grp = rblk >> 3;
    const int pidx = grp * 8 + xcd;
    const bool isZ1 = pidx < 32;
    const int bm = (pidx & 31) * 128, bn = bn_i * 64;
    const bool doZ0 = (!isZ1) && (bn_i == 0);

    if (isZ1) {
        if (t < 64) {
#pragma unroll
            for (int u = 0; u < 4; ++u) {
                union { ushortT us[8]; u32x4 v; } pk;
#pragma unroll
                for (int e = 0; e < 8; ++e) {
                    int k = u * 8 + e;
                    pk.us[e] = (k < 10) ? f2b(W0[(size_t)k * 512 + bn + t]) : (ushortT)0;
                }
                aux[t * 4 + u] = pk.v;
            }
        }
        if (t < 128) {
            union { ushortT us[16]; u32x4 v2[2]; } pk;
#pragma unroll
            for (int e = 0; e < 16; ++e) pk.us[e] = 0;
            const ushortT* sp = sH + (size_t)(bm + t) * HSTR;
#pragma unroll
            for (int e = 0; e < 10; ++e) pk.us[e] = sp[e];
            u32x4 z = {0u, 0u, 0u, 0u};
            aux[256 + t * 4 + 0] = pk.v2[0];
            aux[256 + t * 4 + 1] = pk.v2[1];
            aux[256 + t * 4 + 2] = z;
            aux[256 + t * 4 + 3] = z;
        }
    } else if (doZ0) {
        int c = t >> 4, u0 = (t & 15) * 4;
#pragma unroll
        for (int j = 0; j < 4; ++j) {
            int U = u0 + j;
            union { ushortT us[8]; u32x4 v; } pk;
#pragma unroll
            for (int e = 0; e < 8; ++e)
                pk.us[e] = (c < 10) ? f2b(W0[(size_t)c * 512 + U * 8 + e]) : (ushortT)0;
            aux[c * 64 + ((U & ~7) | ((U & 7) ^ (c & 7)))] = pk.v;
        }
    }

    const int aOff = isZ1 ? OFF2B : OFF1B;
    const int dOff = isZ1 ? OFF1B : OFF2B;
    const int oOff = isZ1 ? 10 : 522;
    const ushortT* __restrict__ Wbh = isZ1 ? W1h : W1Th;
    const ushortT* __restrict__ Wbl = isZ1 ? W1l : W1Tl;
    const int sr = t >> 1, sh = t & 1;
    const int bnr = t >> 2, bju = t & 3;
    const bool fin = (outF != nullptr);

    f32x4 acc[2][4], accZ[2];
#pragma unroll
    for (int mi = 0; mi < 2; ++mi)
#pragma unroll
        for (int ni = 0; ni < 4; ++ni) { f32x4 z = {0.f,0.f,0.f,0.f}; acc[mi][ni] = z; }
#pragma unroll
    for (int i = 0; i < 2; ++i) { f32x4 z = {0.f,0.f,0.f,0.f}; accZ[i] = z; }

    u32x4 rA[2][4], rBh[2][2], rBl[2][2];
    {
        const u32x4* gA = (const u32x4*)(sH + (size_t)(bm + sr) * HSTR + aOff);
        const u32x4* gh = (const u32x4*)(Wbh + (size_t)(bn + bnr) * 512);
        const u32x4* gl = (const u32x4*)(Wbl + (size_t)(bn + bnr) * 512);
#pragma unroll
        for (int j = 0; j < 4; ++j) rA[0][j] = gA[sh * 4 + j];
#pragma unroll
        for (int j = 0; j < 2; ++j) { rBh[0][j] = gh[bju * 2 + j]; rBl[0][j] = gl[bju * 2 + j]; }
    }
#pragma unroll
    for (int it = 0; it < 8; ++it) {
        const int k0 = it * 64;
        const int cur = it & 1, nxt = cur ^ 1;
        __syncthreads();
#pragma unroll
        for (int j = 0; j < 4; ++j) {
            int u = sh * 4 + j;
            AsR[sr * 8 + (u ^ (sr & 7))] = rA[cur][j];
        }
#pragma unroll
        for (int j = 0; j < 2; ++j) {
            int u = bju * 2 + j;
            BhS[bnr * 8 + (u ^ (bnr & 7))] = rBh[cur][j];
            BlS[bnr * 8 + (u ^ (bnr & 7))] = rBl[cur][j];
        }
        if (it < 7) {
            const int k1 = k0 + 64;
            const u32x4* gA = (const u32x4*)(sH + (size_t)(bm + sr) * HSTR + aOff + k1);
            const u32x4* gh = (const u32x4*)(Wbh + (size_t)(bn + bnr) * 512 + k1);
            const u32x4* gl = (const u32x4*)(Wbl + (size_t)(bn + bnr) * 512 + k1);
#pragma unroll
            for (int j = 0; j < 4; ++j) rA[nxt][j] = gA[sh * 4 + j];
#pragma unroll
            for (int j = 0; j < 2; ++j) { rBh[nxt][j] = gh[bju * 2 + j]; rBl[nxt][j] = gl[bju * 2 + j]; }
        }
        __syncthreads();
#pragma unroll
        for (int kw = 0; kw < 2; ++kw) {
            bf16x8 a[2], bh[4], bl[4];
#pragma unroll
            for (int mi = 0; mi < 2; ++mi) {
                int m = mB + mi * 16 + l15;
                a[mi] = BCAST(AsR[m * 8 + ((kw * 4 + l4) ^ (m & 7))]);
            }
#pragma unroll
            for (int ni = 0; ni < 4; ++ni) {
                int n = ni * 16 + l15;
                int u = (kw * 4 + l4) ^ (n & 7);
                bh[ni] = BCAST(BhS[n * 8 + u]);
                bl[ni] = BCAST(BlS[n * 8 + u]);
            }
#pragma unroll
            for (int mi = 0; mi < 2; ++mi)
#pragma unroll
                for (int ni = 0; ni < 4; ++ni) {
                    acc[mi][ni] = MFMA(a[mi], bh[ni], acc[mi][ni]);
                    acc[mi][ni] = MFMA(a[mi], bl[ni], acc[mi][ni]);
                }
            if (doZ0) {
                int U = (k0 >> 3) + kw * 4 + l4;
                bf16x8 bz = BCAST(aux[l15 * 64 + ((U & ~7) | ((U & 7) ^ (l15 & 7)))]);
                accZ[0] = MFMA(a[0], bz, accZ[0]);
                accZ[1] = MFMA(a[1], bz, accZ[1]);
            }
        }
    }
    if (isZ1) {
        bf16x8 a2[2], bb[4];
#pragma unroll
        for (int mi = 0; mi < 2; ++mi)
            a2[mi] = BCAST(aux[256 + (mB + mi * 16 + l15) * 4 + l4]);
#pragma unroll
        for (int ni = 0; ni < 4; ++ni)
            bb[ni] = BCAST(aux[(ni * 16 + l15) * 4 + l4]);
#pragma unroll
        for (int mi = 0; mi < 2; ++mi)
#pragma unroll
            for (int ni = 0; ni < 4; ++ni)
                acc[mi][ni] = MFMA(a2[mi], bb[ni], acc[mi][ni]);
    }

    __syncthreads();
    if (fin) {
#pragma unroll
        for (int ni = 0; ni < 4; ++ni) {
            int gc = bn + ni * 16 + l15;
            float biasN = isZ1 ? b1[gc] : 0.f;
#pragma unroll
            for (int mi = 0; mi < 2; ++mi) {
#pragma unroll
                for (int q = 0; q < 4; ++q) {
                    size_t gb = (size_t)bm + mB + mi * 16 + l4 * 4 + q;
                    float bias = isZ1 ? biasN : c2[gb * 512 + gc];
                    float old = b2f(sH[gb * HSTR + dOff + gc]);
                    float v = 0.5f * old + 0.5f * (acc[mi][ni][q] + bias);
                    v = fminf(fmaxf(v, 0.f), 1.f);
                    outF[gb * CSTR + oOff + gc] = v;
                }
            }
        }
        if (doZ0 && l15 < 10) {
            float b0vv = b0[l15];
#pragma unroll
            for (int i = 0; i < 2; ++i) {
#pragma unroll
                for (int q = 0; q < 4; ++q) {
                    size_t gb = (size_t)bm + w * 32 + i * 16 + l4 * 4 + q;
                    float old = b2f(sH[gb * HSTR + l15]);
                    float v = 0.5f * old + 0.5f * (accZ[i][q] + b0vv);
                    v = fminf(fmaxf(v, 0.f), 1.f);
                    outF[gb * CSTR + l15] = v;
                }
            }
        }
    } else {
        ushortT* dlds = (ushortT*)AsR;
#pragma unroll
        for (int ni = 0; ni < 4; ++ni) {
            int gc = bn + ni * 16 + l15;
            float biasN = isZ1 ? b1[gc] : 0.f;
#pragma unroll
            for (int mi = 0; mi < 2; ++mi) {
#pragma unroll
                for (int q = 0; q < 4; ++q) {
                    size_t gb = (size_t)bm + mB + mi * 16 + l4 * 4 + q;
                    float bias = isZ1 ? biasN : c2[gb * 512 + gc];
                    float old = b2f(sH[gb * HSTR + dOff + gc]);
                    float v = 0.5f * old + 0.5f * (acc[mi][ni][q] + bias);
                    v = fminf(fmaxf(v, 0.f), 1.f);
                    dlds[(mB + mi * 16 + l4 * 4 + q) * 64 + ni * 16 + l15] = f2b(v);
                }
            }
        }
        if (doZ0 && l15 < 10) {
            float b0vv = b0[l15];
#pragma unroll
            for (int i = 0; i < 2; ++i) {
#pragma unroll
                for (int q = 0; q < 4; ++q) {
                    size_t gb = (size_t)bm + w * 32 + i * 16 + l4 * 4 + q;
                    float old = b2f(sH[gb * HSTR + l15]);
                    float v = 0.5f * old + 0.5f * (accZ[i][q] + b0vv);
                    v = fminf(fmaxf(v, 0.f), 1.f);
                    dH[gb * HSTR + l15] = f2b(v);
                }
            }
        }
        __syncthreads();
#pragma unroll
        for (int j = 0; j < 4; ++j) {
            int i = j * 256 + t;
            int row = i >> 3, u = i & 7;
            ((u32x4*)(dH + (size_t)(bm + row) * HSTR + dOff + bn))[u] = AsR[i];
        }
    }
}

extern "C" void kernel_launch(void* const* d_in, const int* in_sizes, int n_in,
                              void* d_out, int out_size, void* d_ws, size_t ws_size,
                              hipStream_t stream) {
    const float* x  = (const float*)d_in[3];
    const float* W0 = (const float*)d_in[4];
    const float* b0 = (const float*)d_in[5];
    const float* W1 = (const float*)d_in[6];
    const float* b1 = (const float*)d_in[7];
    const float* W2 = (const float*)d_in[8];
    const float* b2 = (const float*)d_in[9];

    // buffer A in d_out: 4096*1056*2 = 8,650,752 B <= 16,943,104 B
    ushortT* hiA = (ushortT*)d_out;
    // ws: hiB | c2 f32 | W1h | W1l | W1Th | W1Tl | bar  (~19.1 MB)
    ushortT* hiB = (ushortT*)d_ws;
    float*   c2  = (float*)(hiB + (size_t)4096 * HSTR);
    ushortT* W1h = (ushortT*)(c2 + (size_t)4096 * 512);
    ushortT* W1l  = W1h + 512 * 512;
    ushortT* W1Th = W1l + 512 * 512;
    ushortT* W1Tl = W1Th + 512 * 512;
    unsigned* bar = (unsigned*)(W1Tl + 512 * 512);

    const int zeroN = (int)((size_t)4096 * HSTR * sizeof(ushortT) / sizeof(u32x4));
    k_zero<<<1024, 256, 0, stream>>>((u32x4*)hiA, zeroN, bar);
    k_prep<<<64, 256, 0, stream>>>(W1, W1h, W1l, W1Th, W1Tl);
    k_c2<<<512, 256, 0, stream>>>(x, W2, b2, c2);

    const int DYN = 163840;   // 160 KB LDS per block
    int nb = 0;
    hipError_t e1 = hipFuncSetAttribute((const void*)k_loop2,
                                        hipFuncAttributeMaxDynamicSharedMemorySize, DYN);
    hipError_t e2 = hipOccupancyMaxActiveBlocksPerMultiprocessor(&nb, k_loop2, 512, DYN);
    if (e1 == hipSuccess && e2 == hipSuccess && nb >= 1) {
        k_loop2<<<NBLK2, 512, DYN, stream>>>(hiA, hiB, W1h, W1l, W1Th, W1Tl,
                                             W0, b0, b1, c2, (float*)d_out, bar);
    } else {
        for (int ts = 0; ts < 30; ++ts) {
            const ushortT* sH = (ts & 1) ? hiB : hiA;
            ushortT* dH       = (ts & 1) ? hiA : hiB;
            float* outF = (ts == 29) ? (float*)d_out : nullptr;
            k_step<<<512, 256, 0, stream>>>(sH, dH, W1h, W1l, W1Th, W1Tl,
                                            W0, b0, b1, c2, outF);
        }
    }
}